// Round 2
// baseline (2491.729 us; speedup 1.0000x reference)
//
#include <hip/hip_runtime.h>
#include <hip/hip_bf16.h>
#include <math.h>

// Problem constants
#define L_SEQ 1024
#define BB 2
#define DD 512
#define HH 8
#define DHH 64
#define DFFN 2048
#define NSTATE 16
#define DI 1024
#define DTRANK 32
#define EPSF 1e-5f

typedef __hip_bfloat16 bf16;

__device__ __forceinline__ float bf2f(bf16 v){ return __bfloat162float(v); }
__device__ __forceinline__ bf16 f2bf(float v){ return __float2bfloat16(v); }

// ---------------- dtype detect: majority vote on low-16 exponent of 256 words ----------------
__global__ void k_detect(const unsigned int* __restrict__ w, int* __restrict__ flag){
  __shared__ int cnt;
  if (threadIdx.x==0) cnt = 0;
  __syncthreads();
  unsigned int x = w[threadIdx.x];
  unsigned int low = x & 0xffffu;
  int e = (int)((low >> 7) & 0xffu);
  int vote = (low==0u) || (e >= 110 && e <= 140);
  atomicAdd(&cnt, vote);
  __syncthreads();
  if (threadIdx.x==0) flag[0] = (cnt >= 128) ? 1 : 0;   // 1 = bf16, 0 = fp32
}

// ---------------- fused convert of all inputs to fp32 arena ----------------
#define IN_N 37
struct CvtArgs { const void* src[IN_N]; unsigned int off[IN_N+1]; };

__global__ __launch_bounds__(256) void k_cvt_all(CvtArgs a, float* __restrict__ dst,
                                                 const int* __restrict__ flag, int total){
  const int isbf = flag[0];
  for (int g = blockIdx.x*256 + threadIdx.x; g < total; g += gridDim.x*256){
    int k = 0;
    while (a.off[k+1] <= (unsigned int)g) ++k;
    int e = g - (int)a.off[k];
    float v;
    if (isbf) v = bf2f(((const bf16*)a.src[k])[e]);
    else      v = ((const float*)a.src[k])[e];
    dst[g] = v;
  }
}

// ---------------- generic GEMM: C[M,N] = act(A[M,K] @ W[N,K]^T + bias) ----------------
// act: 0 none, 1 relu, 2 gelu(exact), 3 softplus
__global__ __launch_bounds__(256) void k_gemm(
    const float* __restrict__ A, int lda,
    const float* __restrict__ W,
    const float* __restrict__ bias,
    float* __restrict__ C, int Nn, int K, int act)
{
  __shared__ float As[16][65];
  __shared__ float Ws[16][65];
  const int tid = threadIdx.x;
  const int tx = tid & 15, ty = tid >> 4;
  const int row0 = blockIdx.y << 6, col0 = blockIdx.x << 6;
  float acc[4][4] = {{0.f}};
  const int mload = tid >> 2, kload = (tid & 3) << 2;
  for (int k0 = 0; k0 < K; k0 += 16) {
    float4 av = *reinterpret_cast<const float4*>(&A[(size_t)(row0 + mload)*lda + k0 + kload]);
    As[kload+0][mload]=av.x; As[kload+1][mload]=av.y; As[kload+2][mload]=av.z; As[kload+3][mload]=av.w;
    float4 wv = *reinterpret_cast<const float4*>(&W[(size_t)(col0 + mload)*K + k0 + kload]);
    Ws[kload+0][mload]=wv.x; Ws[kload+1][mload]=wv.y; Ws[kload+2][mload]=wv.z; Ws[kload+3][mload]=wv.w;
    __syncthreads();
    #pragma unroll
    for (int kk = 0; kk < 16; ++kk) {
      float a[4], b[4];
      #pragma unroll
      for (int i=0;i<4;++i){ a[i]=As[kk][(ty<<2)+i]; b[i]=Ws[kk][(tx<<2)+i]; }
      #pragma unroll
      for (int i=0;i<4;++i)
        #pragma unroll
        for (int j=0;j<4;++j)
          acc[i][j] = fmaf(a[i], b[j], acc[i][j]);
    }
    __syncthreads();
  }
  #pragma unroll
  for (int i=0;i<4;++i){
    #pragma unroll
    for (int j=0;j<4;++j){
      float v = acc[i][j];
      if (bias) v += bias[col0 + (tx<<2) + j];
      if (act==1) v = fmaxf(v, 0.f);
      else if (act==2) v = 0.5f*v*(1.f + erff(v*0.70710678118654752f));
      else if (act==3) v = fmaxf(v,0.f) + log1pf(__expf(-fabsf(v)));
      C[(size_t)(row0 + (ty<<2) + i)*Nn + col0 + (tx<<2) + j] = v;
    }
  }
}

// ---------------- attention scores: S[z, q, k] = scale * sum_d Q[q,d] K[k,d] ----------------
__global__ __launch_bounds__(256) void k_attn_scores(
    const float* __restrict__ Qb, int ldq,
    const float* __restrict__ Kb, int ldk,
    float* __restrict__ S, float scale)
{
  __shared__ float Qs[16][65];
  __shared__ float Ks[16][65];
  const int tid = threadIdx.x;
  const int tx = tid & 15, ty = tid >> 4;
  const int kp0 = blockIdx.x << 6;
  const int q0  = blockIdx.y << 6;
  const int z = blockIdx.z; const int b = z >> 3; const int hoff = (z & 7) << 6;
  float acc[4][4] = {{0.f}};
  const int mload = tid >> 2, kload = (tid & 3) << 2;
  for (int k0 = 0; k0 < DHH; k0 += 16) {
    float4 qv = *reinterpret_cast<const float4*>(&Qb[(size_t)((q0+mload)*BB + b)*ldq + hoff + k0 + kload]);
    Qs[kload+0][mload]=qv.x; Qs[kload+1][mload]=qv.y; Qs[kload+2][mload]=qv.z; Qs[kload+3][mload]=qv.w;
    float4 kv = *reinterpret_cast<const float4*>(&Kb[(size_t)((kp0+mload)*BB + b)*ldk + hoff + k0 + kload]);
    Ks[kload+0][mload]=kv.x; Ks[kload+1][mload]=kv.y; Ks[kload+2][mload]=kv.z; Ks[kload+3][mload]=kv.w;
    __syncthreads();
    #pragma unroll
    for (int kk = 0; kk < 16; ++kk) {
      float a[4], b4[4];
      #pragma unroll
      for (int i=0;i<4;++i){ a[i]=Qs[kk][(ty<<2)+i]; b4[i]=Ks[kk][(tx<<2)+i]; }
      #pragma unroll
      for (int i=0;i<4;++i)
        #pragma unroll
        for (int j=0;j<4;++j)
          acc[i][j] = fmaf(a[i], b4[j], acc[i][j]);
    }
    __syncthreads();
  }
  float* Sp = S + (size_t)z*L_SEQ*L_SEQ;
  #pragma unroll
  for (int i=0;i<4;++i)
    #pragma unroll
    for (int j=0;j<4;++j)
      Sp[(size_t)(q0 + (ty<<2) + i)*L_SEQ + kp0 + (tx<<2) + j] = acc[i][j]*scale;
}

// ---------------- row softmax (rows of length 1024) ----------------
__global__ __launch_bounds__(256) void k_softmax(float* __restrict__ S){
  const int row = blockIdx.x;
  float* p = S + (size_t)row*L_SEQ;
  const int tid = threadIdx.x;
  float v0=p[tid], v1=p[tid+256], v2=p[tid+512], v3=p[tid+768];
  __shared__ float red[256];
  red[tid] = fmaxf(fmaxf(v0,v1),fmaxf(v2,v3)); __syncthreads();
  for (int s=128;s>0;s>>=1){ if(tid<s) red[tid]=fmaxf(red[tid],red[tid+s]); __syncthreads(); }
  float m = red[0]; __syncthreads();
  v0=__expf(v0-m); v1=__expf(v1-m); v2=__expf(v2-m); v3=__expf(v3-m);
  red[tid]=v0+v1+v2+v3; __syncthreads();
  for (int s=128;s>0;s>>=1){ if(tid<s) red[tid]+=red[tid+s]; __syncthreads(); }
  float inv = 1.f/red[0];
  p[tid]=v0*inv; p[tid+256]=v1*inv; p[tid+512]=v2*inv; p[tid+768]=v3*inv;
}

// ---------------- mean over heads -> output (dtype per flag) ----------------
__global__ __launch_bounds__(256) void k_attn_mean(const float* __restrict__ S, void* __restrict__ out,
                                                   const int* __restrict__ flag){
  int idx = blockIdx.x*256 + threadIdx.x;  // B*L*L = 2M
  int b = idx >> 20; int rem = idx & ((1<<20)-1);
  const float* p = S + (size_t)b*HH*L_SEQ*L_SEQ + rem;
  float s = 0.f;
  #pragma unroll
  for (int h=0;h<HH;++h) s += p[(size_t)h*L_SEQ*L_SEQ];
  s *= 0.125f;
  size_t o = (size_t)(1u<<20) + (size_t)idx;   // attn starts after 1M tgt elements
  if (flag[0]) ((bf16*)out)[o] = f2bf(s);
  else         ((float*)out)[o] = s;
}

// ---------------- A @ V : O[(q*B+b)*DD + hoff + d] ----------------
__global__ __launch_bounds__(256) void k_attn_av(
    const float* __restrict__ S, const float* __restrict__ Vb, int ldv, int voff,
    float* __restrict__ O)
{
  __shared__ float As[16][65];
  __shared__ float Vs[16][65];
  const int tid = threadIdx.x;
  const int tx = tid & 15, ty = tid >> 4;
  const int q0 = blockIdx.x << 6;
  const int z = blockIdx.y; const int b = z>>3; const int hoff = (z&7)<<6;
  const float* Sp = S + (size_t)z*L_SEQ*L_SEQ;
  float acc[4][4]={{0.f}};
  const int mload = tid>>2, kload4 = (tid&3)<<2;
  const int vk = tid>>4, vd4 = (tid&15)<<2;
  for (int k0=0;k0<L_SEQ;k0+=16){
    float4 av = *reinterpret_cast<const float4*>(&Sp[(size_t)(q0+mload)*L_SEQ + k0 + kload4]);
    As[kload4+0][mload]=av.x; As[kload4+1][mload]=av.y; As[kload4+2][mload]=av.z; As[kload4+3][mload]=av.w;
    float4 vv = *reinterpret_cast<const float4*>(&Vb[(size_t)((k0+vk)*BB + b)*ldv + voff + hoff + vd4]);
    Vs[vk][vd4+0]=vv.x; Vs[vk][vd4+1]=vv.y; Vs[vk][vd4+2]=vv.z; Vs[vk][vd4+3]=vv.w;
    __syncthreads();
    #pragma unroll
    for (int kk = 0; kk < 16; ++kk) {
      float a[4], b4[4];
      #pragma unroll
      for (int i=0;i<4;++i){ a[i]=As[kk][(ty<<2)+i]; b4[i]=Vs[kk][(tx<<2)+i]; }
      #pragma unroll
      for (int i=0;i<4;++i)
        #pragma unroll
        for (int j=0;j<4;++j)
          acc[i][j] = fmaf(a[i], b4[j], acc[i][j]);
    }
    __syncthreads();
  }
  #pragma unroll
  for (int i=0;i<4;++i)
    #pragma unroll
    for (int j=0;j<4;++j)
      O[(size_t)((q0 + (ty<<2) + i)*BB + b)*DD + hoff + (tx<<2) + j] = acc[i][j];
}

// ---------------- x = rmsnorm(x + t2, w) in place ----------------
__global__ __launch_bounds__(256) void k_add_rmsnorm(float* __restrict__ x, const float* __restrict__ t2, const float* __restrict__ w){
  int row = blockIdx.x; size_t base = (size_t)row*DD;
  int tid = threadIdx.x;
  float v0 = x[base+tid] + t2[base+tid];
  float v1 = x[base+tid+256] + t2[base+tid+256];
  __shared__ float red[256];
  red[tid] = v0*v0 + v1*v1; __syncthreads();
  for (int s=128;s>0;s>>=1){ if(tid<s) red[tid]+=red[tid+s]; __syncthreads(); }
  float rms = rsqrtf(red[0]*(1.f/DD) + EPSF);
  x[base+tid]     = v0 * w[tid]     * rms;
  x[base+tid+256] = v1 * w[tid+256] * rms;
}

// ---------------- final: out = rmsnorm(x + t2, w), dtype per flag ----------------
__global__ __launch_bounds__(256) void k_add_rmsnorm_out(const float* __restrict__ x, const float* __restrict__ t2,
                                                         const float* __restrict__ w, void* __restrict__ out,
                                                         const int* __restrict__ flag){
  int row = blockIdx.x; size_t base = (size_t)row*DD;
  int tid = threadIdx.x;
  float v0 = x[base+tid] + t2[base+tid];
  float v1 = x[base+tid+256] + t2[base+tid+256];
  __shared__ float red[256];
  red[tid] = v0*v0 + v1*v1; __syncthreads();
  for (int s=128;s>0;s>>=1){ if(tid<s) red[tid]+=red[tid+s]; __syncthreads(); }
  float rms = rsqrtf(red[0]*(1.f/DD) + EPSF);
  float o0 = v0 * w[tid]     * rms;
  float o1 = v1 * w[tid+256] * rms;
  if (flag[0]){ ((bf16*)out)[base+tid] = f2bf(o0); ((bf16*)out)[base+tid+256] = f2bf(o1); }
  else        { ((float*)out)[base+tid] = o0;      ((float*)out)[base+tid+256] = o1; }
}

// ---------------- xn[b*L+l] = layernorm(tgt[(l*B+b)], w, bias) ----------------
__global__ __launch_bounds__(256) void k_trans_layernorm(const float* __restrict__ tgt, const float* __restrict__ w, const float* __restrict__ bias, float* __restrict__ xn){
  int r = blockIdx.x;        // b*L + l
  int b = r >> 10, l = r & 1023;
  size_t src = ((size_t)l*BB + b)*DD;
  int tid = threadIdx.x;
  float v0 = tgt[src+tid], v1 = tgt[src+tid+256];
  __shared__ float red[256];
  red[tid] = v0 + v1; __syncthreads();
  for (int s=128;s>0;s>>=1){ if(tid<s) red[tid]+=red[tid+s]; __syncthreads(); }
  float mean = red[0]*(1.f/DD);
  __syncthreads();
  red[tid] = v0*v0 + v1*v1; __syncthreads();
  for (int s=128;s>0;s>>=1){ if(tid<s) red[tid]+=red[tid+s]; __syncthreads(); }
  float var = red[0]*(1.f/DD) - mean*mean;
  float rstd = rsqrtf(var + EPSF);
  size_t dst = (size_t)r*DD;
  xn[dst+tid]     = (v0-mean)*rstd*w[tid]     + bias[tid];
  xn[dst+tid+256] = (v1-mean)*rstd*w[tid+256] + bias[tid+256];
}

// ---------------- m[r] = layernorm(yf[r] + yb[flip(r)], w, bias) ----------------
__global__ __launch_bounds__(256) void k_combine_ln(const float* __restrict__ yf, const float* __restrict__ yb, const float* __restrict__ w, const float* __restrict__ bias, float* __restrict__ mo){
  int r = blockIdx.x; int b = r>>10, l = r&1023;
  size_t rf = (size_t)r*DD;
  size_t rb = ((size_t)(b<<10) + (1023 - l))*DD;
  int tid = threadIdx.x;
  float v0 = yf[rf+tid]     + yb[rb+tid];
  float v1 = yf[rf+tid+256] + yb[rb+tid+256];
  __shared__ float red[256];
  red[tid] = v0 + v1; __syncthreads();
  for (int s=128;s>0;s>>=1){ if(tid<s) red[tid]+=red[tid+s]; __syncthreads(); }
  float mean = red[0]*(1.f/DD);
  __syncthreads();
  red[tid] = v0*v0 + v1*v1; __syncthreads();
  for (int s=128;s>0;s>>=1){ if(tid<s) red[tid]+=red[tid+s]; __syncthreads(); }
  float var = red[0]*(1.f/DD) - mean*mean;
  float rstd = rsqrtf(var + EPSF);
  mo[rf+tid]     = (v0-mean)*rstd*w[tid]     + bias[tid];
  mo[rf+tid+256] = (v1-mean)*rstd*w[tid+256] + bias[tid+256];
}

// ---------------- tgt[(l*B+b)] = rmsnorm(2*tgt[(l*B+b)] + ffo[b*L+l], n3_w) ----------------
__global__ __launch_bounds__(256) void k_bimamba_final(float* __restrict__ tgt, const float* __restrict__ ffo, const float* __restrict__ w){
  int r = blockIdx.x; int b = r>>10, l = r&1023;
  size_t t = ((size_t)l*BB + b)*DD;
  size_t f = (size_t)r*DD;
  int tid = threadIdx.x;
  float v0 = 2.f*tgt[t+tid]     + ffo[f+tid];
  float v1 = 2.f*tgt[t+tid+256] + ffo[f+tid+256];
  __shared__ float red[256];
  red[tid] = v0*v0 + v1*v1; __syncthreads();
  for (int s=128;s>0;s>>=1){ if(tid<s) red[tid]+=red[tid+s]; __syncthreads(); }
  float rms = rsqrtf(red[0]*(1.f/DD) + EPSF);
  tgt[t+tid]     = v0 * w[tid]     * rms;
  tgt[t+tid+256] = v1 * w[tid+256] * rms;
}

// ---------------- causal depthwise conv (DCONV=4) + silu ----------------
__global__ __launch_bounds__(256) void k_conv_silu(const float* __restrict__ xz, const float* __restrict__ cw, const float* __restrict__ cb, float* __restrict__ xmc, int rev){
  int idx = blockIdx.x*256 + threadIdx.x;  // B*L*DI = 2M
  int c = idx & 1023;
  int l = (idx >> 10) & 1023;
  int b = idx >> 20;
  float acc = cb[c];
  float w4[4];
  #pragma unroll
  for (int j=0;j<4;++j) w4[j] = cw[(c<<2)+j];
  #pragma unroll
  for (int j=0;j<4;++j){
    int t = l - 3 + j;
    if (t >= 0){
      int src = rev ? (1023 - t) : t;
      acc = fmaf(w4[j], xz[((size_t)(b<<10) + src)*2048 + c], acc);
    }
  }
  xmc[idx] = acc / (1.f + __expf(-acc));
}

// ---------------- selective scan, both directions, 16 states/lane ----------------
__global__ __launch_bounds__(256) void k_scan(
    const float* __restrict__ delta_f, const float* __restrict__ delta_b,
    const float* __restrict__ xmc_f,  const float* __restrict__ xmc_b,
    const float* __restrict__ dbc_f,  const float* __restrict__ dbc_b,
    const float* __restrict__ Alog,
    float* __restrict__ y_f, float* __restrict__ y_b)
{
  int g = blockIdx.x*256 + threadIdx.x;   // 4096 lanes
  int dir = g >> 11;
  int rem = g & 2047;
  int b = rem >> 10;
  int d = rem & 1023;
  const float* delta = dir ? delta_b : delta_f;
  const float* xmc   = dir ? xmc_b   : xmc_f;
  const float* dbc   = dir ? dbc_b   : dbc_f;
  float* y           = dir ? y_b     : y_f;
  float Av[NSTATE];
  #pragma unroll
  for (int n=0;n<NSTATE;++n) Av[n] = -__expf(Alog[d*NSTATE+n]);
  float h[NSTATE];
  #pragma unroll
  for (int n=0;n<NSTATE;++n) h[n]=0.f;
  size_t rowbase = (size_t)(b << 10);
  float dl = delta[(rowbase<<10) + d];
  float x  = xmc[(rowbase<<10) + d];
  for (int t=0;t<1024;++t){
    size_t r = rowbase + t;
    float dl_n = 0.f, x_n = 0.f;
    if (t < 1023){
      size_t i2 = ((r+1)<<10) + d;
      dl_n = delta[i2]; x_n = xmc[i2];
    }
    const float4* bc = reinterpret_cast<const float4*>(dbc + r*64 + 32);
    float Bv[NSTATE], Cv[NSTATE];
    reinterpret_cast<float4*>(Bv)[0]=bc[0]; reinterpret_cast<float4*>(Bv)[1]=bc[1];
    reinterpret_cast<float4*>(Bv)[2]=bc[2]; reinterpret_cast<float4*>(Bv)[3]=bc[3];
    reinterpret_cast<float4*>(Cv)[0]=bc[4]; reinterpret_cast<float4*>(Cv)[1]=bc[5];
    reinterpret_cast<float4*>(Cv)[2]=bc[6]; reinterpret_cast<float4*>(Cv)[3]=bc[7];
    float dx = dl * x;
    float acc = 0.f;
    #pragma unroll
    for (int n=0;n<NSTATE;++n){
      float dA = __expf(dl * Av[n]);
      h[n] = fmaf(dA, h[n], dx * Bv[n]);
      acc = fmaf(h[n], Cv[n], acc);
    }
    y[(r<<10) + d] = acc;
    dl = dl_n; x = x_n;
  }
}

// ---------------- y = (y + Dp*xmc) * silu(z) ----------------
__global__ __launch_bounds__(256) void k_gate(float* __restrict__ y, const float* __restrict__ xmc, const float* __restrict__ xz, const float* __restrict__ Dp, int rev){
  int idx = blockIdx.x*256 + threadIdx.x;  // 2M
  int c = idx & 1023;
  int l = (idx >> 10) & 1023;
  int b = idx >> 20;
  int src = rev ? (1023 - l) : l;
  float z = xz[((size_t)(b<<10)+src)*2048 + 1024 + c];
  float s = z / (1.f + __expf(-z));
  y[idx] = (y[idx] + Dp[c]*xmc[idx]) * s;
}

extern "C" void kernel_launch(void* const* d_in, const int* in_sizes, int n_in,
                              void* d_out, int out_size, void* d_ws, size_t ws_size,
                              hipStream_t stream)
{
  if (n_in < IN_N) return;
  static const unsigned int SZ[IN_N] = {
    1048576,1048576,786432,1536,262144,512,786432,1536,262144,512,
    512,512,512,512,1048576,2048,1048576,512,512,512,
    512,512,1048576,2048,1048576,512,1048576,2048,4096,1024,
    65536,32768,1024,16384,1024,524288,512
  };
  const size_t MF = 1u<<20;           // 1M floats
  if (ws_size < (size_t)35*MF*sizeof(float)) return;   // need 140 MB scratch

  float* ws = (float*)d_ws;
  // fp32 arena for all inputs: [0, 10MF)
  CvtArgs ca;
  unsigned int off = 0;
  for (int i=0;i<IN_N;++i){ ca.src[i] = d_in[i]; ca.off[i] = off; off += SZ[i]; }
  ca.off[IN_N] = off;
  const int total = (int)off;                         // 10,099,200
  int* flag = (int*)(ws + total);                     // still < 10MF

  float* inF = ws;
  #define INP(k) (inF + ca.off[k])
  float* tgt_f   = INP(0);    // running tgt, modified in place
  float* mem_f   = INP(1);    // memory; later reused as ffo
  const float* sa_in_w  = INP(2);  const float* sa_in_b  = INP(3);
  const float* sa_out_w = INP(4);  const float* sa_out_b = INP(5);
  const float* ca_in_w  = INP(6);  const float* ca_in_b  = INP(7);
  const float* ca_out_w = INP(8);  const float* ca_out_b = INP(9);
  const float* n1_w = INP(10); const float* n2_w = INP(11);
  const float* n3_w = INP(12); const float* n4_w = INP(13);
  const float* lin1_w = INP(14); const float* lin1_b = INP(15);
  const float* lin2_w = INP(16); const float* lin2_b = INP(17);
  const float* ln1_w = INP(18); const float* ln1_b = INP(19);
  const float* ln2_w = INP(20); const float* ln2_b = INP(21);
  const float* bff1_w = INP(22); const float* bff1_b = INP(23);
  const float* bff2_w = INP(24); const float* bff2_b = INP(25);
  const float* m_in_w = INP(26); const float* m_in_b = INP(27);
  const float* m_conv_w = INP(28); const float* m_conv_b = INP(29);
  const float* m_xproj_w = INP(30);
  const float* m_dt_w = INP(31); const float* m_dt_b = INP(32);
  const float* m_Alog = INP(33); const float* m_D = INP(34);
  const float* m_out_w = INP(35); const float* m_out_b = INP(36);

  // scratch region: [10MF, 35MF)
  float* t2    = ws + 10*MF;          // 1MF
  float* mbuf  = ws + 11*MF;          // 1MF
  float* proj  = ws + 12*MF;          // 3MF
  float* big   = ws + 15*MF;          // 16MF
  float* ff1   = ws + 31*MF;          // 4MF

  float* qkv     = proj;
  float* scores  = big;
  float* attno   = mbuf;
  float* xn      = t2;
  float* xz      = big;
  float* xmc_f   = big + 4*MF;
  float* xmc_b   = big + 6*MF;
  float* delta_f = big + 8*MF;
  float* delta_b = big + 10*MF;
  float* y_f     = big + 12*MF;
  float* y_b     = big + 14*MF;
  float* dbc_f   = proj;              // 2048*64 floats
  float* dbc_b   = proj + 131072;
  float* yproj_f = proj + 1*MF;
  float* yproj_b = proj + 2*MF;
  float* ffo     = mem_f;

  // detect dtype + convert all inputs to fp32
  k_detect<<<1,256,0,stream>>>((const unsigned int*)d_in[0], flag);
  k_cvt_all<<<4096,256,0,stream>>>(ca, inF, flag, total);

  // ---- self attention ----
  k_gemm<<<dim3(24,32),256,0,stream>>>(tgt_f, DD, sa_in_w, sa_in_b, qkv, 1536, DD, 0);
  k_attn_scores<<<dim3(16,16,16),256,0,stream>>>(qkv, 1536, qkv+512, 1536, scores, 0.125f);
  k_softmax<<<16384,256,0,stream>>>(scores);
  k_attn_av<<<dim3(16,16),256,0,stream>>>(scores, qkv, 1536, 1024, attno);
  k_gemm<<<dim3(8,32),256,0,stream>>>(attno, DD, sa_out_w, sa_out_b, t2, DD, DD, 0);
  k_add_rmsnorm<<<2048,256,0,stream>>>(tgt_f, t2, n1_w);

  // ---- cross attention ----
  k_gemm<<<dim3(8,32),256,0,stream>>>(tgt_f, DD, ca_in_w, ca_in_b, proj, DD, DD, 0);
  k_gemm<<<dim3(16,32),256,0,stream>>>(mem_f, DD, ca_in_w + (size_t)DD*DD, ca_in_b + DD, proj+MF, 1024, DD, 0);
  k_attn_scores<<<dim3(16,16,16),256,0,stream>>>(proj, DD, proj+MF, 1024, scores, 0.125f);
  k_softmax<<<16384,256,0,stream>>>(scores);
  k_attn_mean<<<8192,256,0,stream>>>(scores, d_out, flag);
  k_attn_av<<<dim3(16,16),256,0,stream>>>(scores, proj+MF, 1024, 512, attno);
  k_gemm<<<dim3(8,32),256,0,stream>>>(attno, DD, ca_out_w, ca_out_b, t2, DD, DD, 0);
  k_add_rmsnorm<<<2048,256,0,stream>>>(tgt_f, t2, n2_w);

  // ---- bimamba ----
  k_trans_layernorm<<<2048,256,0,stream>>>(tgt_f, ln1_w, ln1_b, xn);
  k_gemm<<<dim3(32,32),256,0,stream>>>(xn, DD, m_in_w, m_in_b, xz, 2048, DD, 0);
  k_conv_silu<<<8192,256,0,stream>>>(xz, m_conv_w, m_conv_b, xmc_f, 0);
  k_conv_silu<<<8192,256,0,stream>>>(xz, m_conv_w, m_conv_b, xmc_b, 1);
  k_gemm<<<dim3(1,32),256,0,stream>>>(xmc_f, DI, m_xproj_w, nullptr, dbc_f, 64, DI, 0);
  k_gemm<<<dim3(1,32),256,0,stream>>>(xmc_b, DI, m_xproj_w, nullptr, dbc_b, 64, DI, 0);
  k_gemm<<<dim3(16,32),256,0,stream>>>(dbc_f, 64, m_dt_w, m_dt_b, delta_f, DI, DTRANK, 3);
  k_gemm<<<dim3(16,32),256,0,stream>>>(dbc_b, 64, m_dt_w, m_dt_b, delta_b, DI, DTRANK, 3);
  k_scan<<<16,256,0,stream>>>(delta_f, delta_b, xmc_f, xmc_b, dbc_f, dbc_b, m_Alog, y_f, y_b);
  k_gate<<<8192,256,0,stream>>>(y_f, xmc_f, xz, m_D, 0);
  k_gate<<<8192,256,0,stream>>>(y_b, xmc_b, xz, m_D, 1);
  k_gemm<<<dim3(8,32),256,0,stream>>>(y_f, DI, m_out_w, m_out_b, yproj_f, DD, DI, 0);
  k_gemm<<<dim3(8,32),256,0,stream>>>(y_b, DI, m_out_w, m_out_b, yproj_b, DD, DI, 0);
  k_combine_ln<<<2048,256,0,stream>>>(yproj_f, yproj_b, ln2_w, ln2_b, mbuf);
  k_gemm<<<dim3(32,32),256,0,stream>>>(mbuf, DD, bff1_w, bff1_b, ff1, DFFN, DD, 2);
  k_gemm<<<dim3(8,32),256,0,stream>>>(ff1, DFFN, bff2_w, bff2_b, ffo, DD, DFFN, 0);
  k_bimamba_final<<<2048,256,0,stream>>>(tgt_f, ffo, n3_w);

  // ---- final FFN ----
  k_gemm<<<dim3(32,32),256,0,stream>>>(tgt_f, DD, lin1_w, lin1_b, ff1, DFFN, DD, 1);
  k_gemm<<<dim3(8,32),256,0,stream>>>(ff1, DFFN, lin2_w, lin2_b, t2, DD, DFFN, 0);
  k_add_rmsnorm_out<<<2048,256,0,stream>>>(tgt_f, t2, n4_w, d_out, flag);
}

// Round 3
// 906.520 us; speedup vs baseline: 2.7487x; 2.7487x over previous
//
#include <hip/hip_runtime.h>
#include <hip/hip_bf16.h>
#include <math.h>

#define L_SEQ 1024
#define BB 2
#define DD 512
#define HH 8
#define DFFN 2048
#define NSTATE 16
#define DI 1024
#define EPSF 1e-5f

typedef __hip_bfloat16 bf16;
typedef __attribute__((ext_vector_type(8))) short short8v;
typedef __attribute__((ext_vector_type(4))) short short4v;
typedef __attribute__((ext_vector_type(4))) float float4v;

__device__ __forceinline__ float bf2f(bf16 v){ return __bfloat162float(v); }
__device__ __forceinline__ bf16 f2bf(float v){ return __float2bfloat16(v); }
__device__ __forceinline__ short f2bfs(float v){
  bf16 t = __float2bfloat16(v);
  short s; __builtin_memcpy(&s, &t, 2);
  return s;
}

// ---------------- dtype detect ----------------
__global__ void k_detect(const unsigned int* __restrict__ w, int* __restrict__ flag){
  __shared__ int cnt;
  if (threadIdx.x==0) cnt = 0;
  __syncthreads();
  unsigned int x = w[threadIdx.x];
  unsigned int low = x & 0xffffu;
  int e = (int)((low >> 7) & 0xffu);
  int vote = (low==0u) || (e >= 110 && e <= 140);
  atomicAdd(&cnt, vote);
  __syncthreads();
  if (threadIdx.x==0) flag[0] = (cnt >= 128) ? 1 : 0;   // 1 = bf16 inputs, 0 = fp32
}

// ---------------- converts ----------------
struct CvtTabF { const void* src[25]; unsigned int off[26]; };
struct CvtTabW { const void* src[12]; unsigned int off[13]; };

__global__ __launch_bounds__(256) void k_cvt_f32(CvtTabF t, float* __restrict__ dst,
                                                 const int* __restrict__ flag, int total){
  const int isbf = flag[0];
  for (int g = blockIdx.x*256 + threadIdx.x; g < total; g += gridDim.x*256){
    int k = 0;
    while (t.off[k+1] <= (unsigned int)g) ++k;
    int e = g - (int)t.off[k];
    dst[g] = isbf ? bf2f(((const bf16*)t.src[k])[e]) : ((const float*)t.src[k])[e];
  }
}

__global__ __launch_bounds__(256) void k_cvt_b16(CvtTabW t, bf16* __restrict__ dst,
                                                 const int* __restrict__ flag, int total){
  const int isbf = flag[0];
  for (int g = blockIdx.x*256 + threadIdx.x; g < total; g += gridDim.x*256){
    int k = 0;
    while (t.off[k+1] <= (unsigned int)g) ++k;
    int e = g - (int)t.off[k];
    if (isbf) dst[g] = ((const bf16*)t.src[k])[e];
    else      dst[g] = f2bf(((const float*)t.src[k])[e]);
  }
}

// ---------------- batched-strided MFMA bf16 GEMM ----------------
// C[z][m][n] = act( scale * sum_k A[z][m][k]*B[z][n][k] + bias[n] )
// z = zb*H + zh. A fp32. B: cB=0 fp32 row-major n (k contig), cB=1 fp32 k-major (n contig), cB=2 bf16 (k contig)
// Tile: BM=64, BN=64, BK=32, 256 threads = 4 waves, each wave 16 rows x 64 cols.
__global__ __launch_bounds__(256) void k_mfma_gemm(
    const float* __restrict__ Ab, long long sAb, long long sAh, long long sAm,
    const void* __restrict__ Bb, long long sBb, long long sBh, long long sBrow, int cB,
    float* __restrict__ Cb, long long sCb, long long sCh, long long sCm,
    const float* __restrict__ bias, float scale, int act, int K, int H)
{
  __shared__ short As[64*40];
  __shared__ short Bs[64*40];
  const int tid = threadIdx.x;
  const int z = blockIdx.z; const int zb = z / H; const int zh = z % H;
  const int col0 = blockIdx.x << 6, m0 = blockIdx.y << 6;
  const float* Abase = Ab + zb*sAb + zh*sAh;
  const float* Bf = (const float*)Bb;
  const bf16* Bw = (const bf16*)Bb;
  const long long boff = zb*sBb + zh*sBh;
  float4v acc[4];
  #pragma unroll
  for (int i=0;i<4;++i) acc[i] = (float4v)(0.f);
  const int lane = tid & 63, w = tid >> 6;
  const int lr = lane & 15, quad = lane >> 4;

  for (int k0 = 0; k0 < K; k0 += 32){
    // stage A (fp32 -> bf16 LDS [m][k], stride 40)
    #pragma unroll
    for (int i=0;i<2;++i){
      int g = tid + i*256;
      int row = g >> 3, k4 = (g & 7) << 2;
      float4 v = *(const float4*)&Abase[(long long)(m0+row)*sAm + k0 + k4];
      short4v s4; s4.x=f2bfs(v.x); s4.y=f2bfs(v.y); s4.z=f2bfs(v.z); s4.w=f2bfs(v.w);
      *(short4v*)&As[row*40 + k4] = s4;
    }
    // stage B
    if (cB == 2){
      int row = tid >> 2, k8 = (tid & 3) << 3;
      short8v v = *(const short8v*)&Bw[boff + (long long)(col0+row)*sBrow + k0 + k8];
      *(short8v*)&Bs[row*40 + k8] = v;
    } else if (cB == 0){
      #pragma unroll
      for (int i=0;i<2;++i){
        int g = tid + i*256;
        int row = g >> 3, k4 = (g & 7) << 2;
        float4 v = *(const float4*)&Bf[boff + (long long)(col0+row)*sBrow + k0 + k4];
        short4v s4; s4.x=f2bfs(v.x); s4.y=f2bfs(v.y); s4.z=f2bfs(v.z); s4.w=f2bfs(v.w);
        *(short4v*)&Bs[row*40 + k4] = s4;
      }
    } else {
      #pragma unroll
      for (int i=0;i<2;++i){
        int g = tid + i*256;
        int k = g >> 4, n4 = (g & 15) << 2;
        float4 v = *(const float4*)&Bf[boff + (long long)(k0+k)*sBrow + col0 + n4];
        Bs[(n4+0)*40 + k] = f2bfs(v.x);
        Bs[(n4+1)*40 + k] = f2bfs(v.y);
        Bs[(n4+2)*40 + k] = f2bfs(v.z);
        Bs[(n4+3)*40 + k] = f2bfs(v.w);
      }
    }
    __syncthreads();
    short8v a = *(short8v*)&As[(w*16 + lr)*40 + quad*8];
    #pragma unroll
    for (int cb=0; cb<4; ++cb){
      short8v bfr = *(short8v*)&Bs[(cb*16 + lr)*40 + quad*8];
      acc[cb] = __builtin_amdgcn_mfma_f32_16x16x32_bf16(a, bfr, acc[cb], 0, 0, 0);
    }
    __syncthreads();
  }
  float* Crow = Cb + zb*sCb + zh*sCh;
  #pragma unroll
  for (int cb=0; cb<4; ++cb){
    #pragma unroll
    for (int r=0;r<4;++r){
      int m = m0 + w*16 + quad*4 + r;
      int n = col0 + cb*16 + lr;
      float v = acc[cb][r] * scale;
      if (bias) v += bias[n];
      if (act==1) v = fmaxf(v,0.f);
      else if (act==2) v = 0.5f*v*(1.f + erff(v*0.70710678118654752f));
      else if (act==3) v = fmaxf(v,0.f) + log1pf(__expf(-fabsf(v)));
      Crow[(long long)m*sCm + n] = v;
    }
  }
}

// ---------------- row softmax (rows of length 1024) ----------------
__global__ __launch_bounds__(256) void k_softmax(float* __restrict__ S){
  const int row = blockIdx.x;
  float* p = S + (size_t)row*L_SEQ;
  const int tid = threadIdx.x;
  float v0=p[tid], v1=p[tid+256], v2=p[tid+512], v3=p[tid+768];
  __shared__ float red[256];
  red[tid] = fmaxf(fmaxf(v0,v1),fmaxf(v2,v3)); __syncthreads();
  for (int s=128;s>0;s>>=1){ if(tid<s) red[tid]=fmaxf(red[tid],red[tid+s]); __syncthreads(); }
  float m = red[0]; __syncthreads();
  v0=__expf(v0-m); v1=__expf(v1-m); v2=__expf(v2-m); v3=__expf(v3-m);
  red[tid]=v0+v1+v2+v3; __syncthreads();
  for (int s=128;s>0;s>>=1){ if(tid<s) red[tid]+=red[tid+s]; __syncthreads(); }
  float inv = 1.f/red[0];
  p[tid]=v0*inv; p[tid+256]=v1*inv; p[tid+512]=v2*inv; p[tid+768]=v3*inv;
}

// ---------------- mean over heads -> output ----------------
__global__ __launch_bounds__(256) void k_attn_mean(const float* __restrict__ S, void* __restrict__ out,
                                                   const int* __restrict__ flag){
  int idx = blockIdx.x*256 + threadIdx.x;  // 2M
  int b = idx >> 20; int rem = idx & ((1<<20)-1);
  const float* p = S + (size_t)b*HH*L_SEQ*L_SEQ + rem;
  float s = 0.f;
  #pragma unroll
  for (int h=0;h<HH;++h) s += p[(size_t)h*L_SEQ*L_SEQ];
  s *= 0.125f;
  size_t o = (size_t)(1u<<20) + (size_t)idx;
  if (flag[0]) ((bf16*)out)[o] = f2bf(s);
  else         ((float*)out)[o] = s;
}

// ---------------- norms / elementwise ----------------
__global__ __launch_bounds__(256) void k_add_rmsnorm(float* __restrict__ x, const float* __restrict__ t2, const float* __restrict__ w){
  int row = blockIdx.x; size_t base = (size_t)row*DD;
  int tid = threadIdx.x;
  float v0 = x[base+tid] + t2[base+tid];
  float v1 = x[base+tid+256] + t2[base+tid+256];
  __shared__ float red[256];
  red[tid] = v0*v0 + v1*v1; __syncthreads();
  for (int s=128;s>0;s>>=1){ if(tid<s) red[tid]+=red[tid+s]; __syncthreads(); }
  float rms = rsqrtf(red[0]*(1.f/DD) + EPSF);
  x[base+tid]     = v0 * w[tid]     * rms;
  x[base+tid+256] = v1 * w[tid+256] * rms;
}

__global__ __launch_bounds__(256) void k_add_rmsnorm_out(const float* __restrict__ x, const float* __restrict__ t2,
                                                         const float* __restrict__ w, void* __restrict__ out,
                                                         const int* __restrict__ flag){
  int row = blockIdx.x; size_t base = (size_t)row*DD;
  int tid = threadIdx.x;
  float v0 = x[base+tid] + t2[base+tid];
  float v1 = x[base+tid+256] + t2[base+tid+256];
  __shared__ float red[256];
  red[tid] = v0*v0 + v1*v1; __syncthreads();
  for (int s=128;s>0;s>>=1){ if(tid<s) red[tid]+=red[tid+s]; __syncthreads(); }
  float rms = rsqrtf(red[0]*(1.f/DD) + EPSF);
  float o0 = v0 * w[tid]     * rms;
  float o1 = v1 * w[tid+256] * rms;
  if (flag[0]){ ((bf16*)out)[base+tid] = f2bf(o0); ((bf16*)out)[base+tid+256] = f2bf(o1); }
  else        { ((float*)out)[base+tid] = o0;      ((float*)out)[base+tid+256] = o1; }
}

__global__ __launch_bounds__(256) void k_trans_layernorm(const float* __restrict__ tgt, const float* __restrict__ w, const float* __restrict__ bias, float* __restrict__ xn){
  int r = blockIdx.x;        // b*L + l
  int b = r >> 10, l = r & 1023;
  size_t src = ((size_t)l*BB + b)*DD;
  int tid = threadIdx.x;
  float v0 = tgt[src+tid], v1 = tgt[src+tid+256];
  __shared__ float red[256];
  red[tid] = v0 + v1; __syncthreads();
  for (int s=128;s>0;s>>=1){ if(tid<s) red[tid]+=red[tid+s]; __syncthreads(); }
  float mean = red[0]*(1.f/DD);
  __syncthreads();
  red[tid] = v0*v0 + v1*v1; __syncthreads();
  for (int s=128;s>0;s>>=1){ if(tid<s) red[tid]+=red[tid+s]; __syncthreads(); }
  float var = red[0]*(1.f/DD) - mean*mean;
  float rstd = rsqrtf(var + EPSF);
  size_t dst = (size_t)r*DD;
  xn[dst+tid]     = (v0-mean)*rstd*w[tid]     + bias[tid];
  xn[dst+tid+256] = (v1-mean)*rstd*w[tid+256] + bias[tid+256];
}

__global__ __launch_bounds__(256) void k_combine_ln(const float* __restrict__ yf, const float* __restrict__ yb, const float* __restrict__ w, const float* __restrict__ bias, float* __restrict__ mo){
  int r = blockIdx.x; int b = r>>10, l = r&1023;
  size_t rf = (size_t)r*DD;
  size_t rb = ((size_t)(b<<10) + (1023 - l))*DD;
  int tid = threadIdx.x;
  float v0 = yf[rf+tid]     + yb[rb+tid];
  float v1 = yf[rf+tid+256] + yb[rb+tid+256];
  __shared__ float red[256];
  red[tid] = v0 + v1; __syncthreads();
  for (int s=128;s>0;s>>=1){ if(tid<s) red[tid]+=red[tid+s]; __syncthreads(); }
  float mean = red[0]*(1.f/DD);
  __syncthreads();
  red[tid] = v0*v0 + v1*v1; __syncthreads();
  for (int s=128;s>0;s>>=1){ if(tid<s) red[tid]+=red[tid+s]; __syncthreads(); }
  float var = red[0]*(1.f/DD) - mean*mean;
  float rstd = rsqrtf(var + EPSF);
  mo[rf+tid]     = (v0-mean)*rstd*w[tid]     + bias[tid];
  mo[rf+tid+256] = (v1-mean)*rstd*w[tid+256] + bias[tid+256];
}

__global__ __launch_bounds__(256) void k_bimamba_final(float* __restrict__ tgt, const float* __restrict__ ffo, const float* __restrict__ w){
  int r = blockIdx.x; int b = r>>10, l = r&1023;
  size_t t = ((size_t)l*BB + b)*DD;
  size_t f = (size_t)r*DD;
  int tid = threadIdx.x;
  float v0 = 2.f*tgt[t+tid]     + ffo[f+tid];
  float v1 = 2.f*tgt[t+tid+256] + ffo[f+tid+256];
  __shared__ float red[256];
  red[tid] = v0*v0 + v1*v1; __syncthreads();
  for (int s=128;s>0;s>>=1){ if(tid<s) red[tid]+=red[tid+s]; __syncthreads(); }
  float rms = rsqrtf(red[0]*(1.f/DD) + EPSF);
  tgt[t+tid]     = v0 * w[tid]     * rms;
  tgt[t+tid+256] = v1 * w[tid+256] * rms;
}

// ---------------- causal depthwise conv + silu ----------------
__global__ __launch_bounds__(256) void k_conv_silu(const float* __restrict__ xz, const float* __restrict__ cw, const float* __restrict__ cb, float* __restrict__ xmc, int rev){
  int idx = blockIdx.x*256 + threadIdx.x;  // 2M
  int c = idx & 1023;
  int l = (idx >> 10) & 1023;
  int b = idx >> 20;
  float acc = cb[c];
  float w4[4];
  #pragma unroll
  for (int j=0;j<4;++j) w4[j] = cw[(c<<2)+j];
  #pragma unroll
  for (int j=0;j<4;++j){
    int t = l - 3 + j;
    if (t >= 0){
      int src = rev ? (1023 - t) : t;
      acc = fmaf(w4[j], xz[((size_t)(b<<10) + src)*2048 + c], acc);
    }
  }
  xmc[idx] = acc / (1.f + __expf(-acc));
}

// ---------------- chunked selective scan ----------------
// channel = dir*2048 + b*1024 + d; 32 chunks of 32 steps
__global__ __launch_bounds__(256) void k_scan1(
    const float* __restrict__ delta_f, const float* __restrict__ delta_b,
    const float* __restrict__ xmc_f,  const float* __restrict__ xmc_b,
    const float* __restrict__ dbc_f,  const float* __restrict__ dbc_b,
    const float* __restrict__ Alog,
    float* __restrict__ hend, float* __restrict__ Sdl)
{
  int ch = blockIdx.x*256 + threadIdx.x;
  int c = blockIdx.y;
  int dir = ch >> 11, b = (ch >> 10) & 1, d = ch & 1023;
  const float* delta = dir ? delta_b : delta_f;
  const float* xmc   = dir ? xmc_b   : xmc_f;
  const float* dbc   = dir ? dbc_b   : dbc_f;
  float Av[NSTATE];
  #pragma unroll
  for (int n=0;n<NSTATE;++n) Av[n] = -__expf(Alog[d*NSTATE+n]);
  float h[NSTATE];
  #pragma unroll
  for (int n=0;n<NSTATE;++n) h[n]=0.f;
  float S = 0.f;
  int r0 = b*1024 + c*32;
  for (int t=0;t<32;++t){
    int r = r0 + t;
    float dl = delta[((size_t)r<<10) + d];
    float x  = xmc[((size_t)r<<10) + d];
    const float4* bp = (const float4*)(dbc + (size_t)r*64 + 32);
    float Bv[NSTATE];
    ((float4*)Bv)[0]=bp[0]; ((float4*)Bv)[1]=bp[1]; ((float4*)Bv)[2]=bp[2]; ((float4*)Bv)[3]=bp[3];
    S += dl;
    float dx = dl*x;
    #pragma unroll
    for (int n=0;n<NSTATE;++n){
      float dA = __expf(dl*Av[n]);
      h[n] = fmaf(dA, h[n], dx*Bv[n]);
    }
  }
  size_t base = ((size_t)c*4096 + ch)*16;
  #pragma unroll
  for (int n=0;n<NSTATE;++n) hend[base+n] = h[n];
  Sdl[c*4096 + ch] = S;
}

__global__ __launch_bounds__(256) void k_scan_carry(const float* __restrict__ Alog,
                                                    float* __restrict__ hh, const float* __restrict__ Sdl)
{
  int ch = blockIdx.x*256 + threadIdx.x;
  int d = ch & 1023;
  float Av[NSTATE];
  #pragma unroll
  for (int n=0;n<NSTATE;++n) Av[n] = -__expf(Alog[d*NSTATE+n]);
  float h[NSTATE];
  #pragma unroll
  for (int n=0;n<NSTATE;++n) h[n]=0.f;
  for (int c=0;c<32;++c){
    size_t base = ((size_t)c*4096 + ch)*16;
    float S = Sdl[c*4096 + ch];
    float he[NSTATE];
    #pragma unroll
    for (int n=0;n<NSTATE;++n) he[n] = hh[base+n];
    #pragma unroll
    for (int n=0;n<NSTATE;++n) hh[base+n] = h[n];     // carry-in for chunk c (in place)
    #pragma unroll
    for (int n=0;n<NSTATE;++n) h[n] = fmaf(__expf(Av[n]*S), h[n], he[n]);
  }
}

__global__ __launch_bounds__(256) void k_scan2(
    const float* __restrict__ delta_f, const float* __restrict__ delta_b,
    const float* __restrict__ xmc_f,  const float* __restrict__ xmc_b,
    const float* __restrict__ dbc_f,  const float* __restrict__ dbc_b,
    const float* __restrict__ Alog,   const float* __restrict__ hin,
    float* __restrict__ y_f, float* __restrict__ y_b)
{
  int ch = blockIdx.x*256 + threadIdx.x;
  int c = blockIdx.y;
  int dir = ch >> 11, b = (ch >> 10) & 1, d = ch & 1023;
  const float* delta = dir ? delta_b : delta_f;
  const float* xmc   = dir ? xmc_b   : xmc_f;
  const float* dbc   = dir ? dbc_b   : dbc_f;
  float* y           = dir ? y_b     : y_f;
  float Av[NSTATE];
  #pragma unroll
  for (int n=0;n<NSTATE;++n) Av[n] = -__expf(Alog[d*NSTATE+n]);
  float h[NSTATE];
  size_t cbase = ((size_t)c*4096 + ch)*16;
  #pragma unroll
  for (int n=0;n<NSTATE;++n) h[n] = hin[cbase+n];
  int r0 = b*1024 + c*32;
  for (int t=0;t<32;++t){
    int r = r0 + t;
    float dl = delta[((size_t)r<<10) + d];
    float x  = xmc[((size_t)r<<10) + d];
    const float4* bp = (const float4*)(dbc + (size_t)r*64 + 32);
    float Bv[NSTATE], Cv[NSTATE];
    ((float4*)Bv)[0]=bp[0]; ((float4*)Bv)[1]=bp[1]; ((float4*)Bv)[2]=bp[2]; ((float4*)Bv)[3]=bp[3];
    ((float4*)Cv)[0]=bp[4]; ((float4*)Cv)[1]=bp[5]; ((float4*)Cv)[2]=bp[6]; ((float4*)Cv)[3]=bp[7];
    float dx = dl*x;
    float acc = 0.f;
    #pragma unroll
    for (int n=0;n<NSTATE;++n){
      float dA = __expf(dl*Av[n]);
      h[n] = fmaf(dA, h[n], dx*Bv[n]);
      acc = fmaf(h[n], Cv[n], acc);
    }
    y[((size_t)r<<10) + d] = acc;
  }
}

// ---------------- y = (y + Dp*xmc) * silu(z) ----------------
__global__ __launch_bounds__(256) void k_gate(float* __restrict__ y, const float* __restrict__ xmc, const float* __restrict__ xz, const float* __restrict__ Dp, int rev){
  int idx = blockIdx.x*256 + threadIdx.x;  // 2M
  int c = idx & 1023;
  int l = (idx >> 10) & 1023;
  int b = idx >> 20;
  int src = rev ? (1023 - l) : l;
  float z = xz[((size_t)(b<<10)+src)*2048 + 1024 + c];
  float s = z / (1.f + __expf(-z));
  y[idx] = (y[idx] + Dp[c]*xmc[idx]) * s;
}

extern "C" void kernel_launch(void* const* d_in, const int* in_sizes, int n_in,
                              void* d_out, int out_size, void* d_ws, size_t ws_size,
                              hipStream_t stream)
{
  if (n_in < 37) return;
  static const unsigned int SZ[37] = {
    1048576,1048576,786432,1536,262144,512,786432,1536,262144,512,
    512,512,512,512,1048576,2048,1048576,512,512,512,
    512,512,1048576,2048,1048576,512,1048576,2048,4096,1024,
    65536,32768,1024,16384,1024,524288,512
  };
  static const unsigned char ISW[37] = {
    0,0,1,0,1,0,1,0,1,0, 0,0,0,0,1,0,1,0,0,0,
    0,0,1,0,1,0,1,0,0,0, 1,1,0,0,0,1,0
  };
  const long long MF = 1u<<20;
  if (ws_size < (size_t)(32*MF)*sizeof(float)) return;   // 128 MB

  float* ws = (float*)d_ws;
  float* inF = ws;                       // fp32 params arena  [0, 3MF)
  bf16*  inB = (bf16*)(ws + 3*MF);       // bf16 weight arena  [3MF, 7MF)
  float* t2    = ws + 7*MF;
  float* mbuf  = ws + 8*MF;
  float* proj  = ws + 9*MF;              // 3MF
  float* big   = ws + 12*MF;             // 16MF
  float* ff1   = ws + 28*MF;             // 4MF (scan carries overlap here pre-FFN)

  CvtTabF tf; CvtTabW tb;
  unsigned int fOff[37], bOff[37];
  {
    int nf=0, nb=0; unsigned int of=0, ob=0;
    for (int i=0;i<37;++i){
      if (ISW[i]){ tb.src[nb]=d_in[i]; tb.off[nb]=ob; bOff[i]=ob; ob+=SZ[i]; ++nb; }
      else       { tf.src[nf]=d_in[i]; tf.off[nf]=of; fOff[i]=of; of+=SZ[i]; ++nf; }
    }
    tf.off[25]=of; tb.off[12]=ob;
    int* flag = (int*)(ws + 3*MF - 16);

    #define PF(i) (inF + fOff[i])
    #define PW(i) (inB + bOff[i])

    float* tgt_f = PF(0);
    float* mem_f = PF(1);                // dead after CA kv proj -> reused as ffo
    float* qkv     = proj;               // 3MF
    float* scores  = big;                // 16MF
    float* attno   = mbuf;
    float* xn      = t2;
    float* xz      = big;
    float* xmc_f   = big + 4*MF;
    float* xmc_b   = big + 6*MF;
    float* delta_f = big + 8*MF;
    float* delta_b = big + 10*MF;
    float* y_f     = big + 12*MF;
    float* y_b     = big + 14*MF;
    float* dbc_f   = proj;
    float* dbc_b   = proj + 131072;
    float* yproj_f = proj + 1*MF;
    float* yproj_b = proj + 2*MF;
    float* ffo     = mem_f;
    float* hend    = ff1;                // 2MF (carries; dead before bff1)
    float* Sdl     = ff1 + 2*MF;         // 128K

    k_detect<<<1,256,0,stream>>>((const unsigned int*)d_in[0], flag);
    k_cvt_f32<<<2048,256,0,stream>>>(tf, inF, flag, (int)of);
    k_cvt_b16<<<4096,256,0,stream>>>(tb, inB, flag, (int)ob);

    // ---- self attention ----
    k_mfma_gemm<<<dim3(24,32,1),256,0,stream>>>(tgt_f,0,0,512, PW(2),0,0,512,2, qkv,0,0,1536, PF(3),1.f,0,512,1);
    k_mfma_gemm<<<dim3(16,16,16),256,0,stream>>>(qkv,1536,64,3072, qkv+512,1536,64,3072,0, scores,8*MF,MF,1024, nullptr,0.125f,0,64,8);
    k_softmax<<<16384,256,0,stream>>>(scores);
    k_mfma_gemm<<<dim3(1,16,16),256,0,stream>>>(scores,8*MF,MF,1024, qkv+1024,1536,64,3072,1, attno,512,64,1024, nullptr,1.f,0,1024,8);
    k_mfma_gemm<<<dim3(8,32,1),256,0,stream>>>(attno,0,0,512, PW(4),0,0,512,2, t2,0,0,512, PF(5),1.f,0,512,1);
    k_add_rmsnorm<<<2048,256,0,stream>>>(tgt_f, t2, PF(10));

    // ---- cross attention ----
    k_mfma_gemm<<<dim3(8,32,1),256,0,stream>>>(tgt_f,0,0,512, PW(6),0,0,512,2, proj,0,0,512, PF(7),1.f,0,512,1);
    k_mfma_gemm<<<dim3(16,32,1),256,0,stream>>>(mem_f,0,0,512, PW(6)+(size_t)512*512,0,0,512,2, proj+MF,0,0,1024, PF(7)+512,1.f,0,512,1);
    k_mfma_gemm<<<dim3(16,16,16),256,0,stream>>>(proj,512,64,1024, proj+MF,1024,64,2048,0, scores,8*MF,MF,1024, nullptr,0.125f,0,64,8);
    k_softmax<<<16384,256,0,stream>>>(scores);
    k_attn_mean<<<8192,256,0,stream>>>(scores, d_out, flag);
    k_mfma_gemm<<<dim3(1,16,16),256,0,stream>>>(scores,8*MF,MF,1024, proj+MF+512,1024,64,2048,1, attno,512,64,1024, nullptr,1.f,0,1024,8);
    k_mfma_gemm<<<dim3(8,32,1),256,0,stream>>>(attno,0,0,512, PW(8),0,0,512,2, t2,0,0,512, PF(9),1.f,0,512,1);
    k_add_rmsnorm<<<2048,256,0,stream>>>(tgt_f, t2, PF(11));

    // ---- bimamba ----
    k_trans_layernorm<<<2048,256,0,stream>>>(tgt_f, PF(18), PF(19), xn);
    k_mfma_gemm<<<dim3(32,32,1),256,0,stream>>>(xn,0,0,512, PW(26),0,0,512,2, xz,0,0,2048, PF(27),1.f,0,512,1);
    k_conv_silu<<<8192,256,0,stream>>>(xz, PF(28), PF(29), xmc_f, 0);
    k_conv_silu<<<8192,256,0,stream>>>(xz, PF(28), PF(29), xmc_b, 1);
    k_mfma_gemm<<<dim3(1,32,1),256,0,stream>>>(xmc_f,0,0,1024, PW(30),0,0,1024,2, dbc_f,0,0,64, nullptr,1.f,0,1024,1);
    k_mfma_gemm<<<dim3(1,32,1),256,0,stream>>>(xmc_b,0,0,1024, PW(30),0,0,1024,2, dbc_b,0,0,64, nullptr,1.f,0,1024,1);
    k_mfma_gemm<<<dim3(16,32,1),256,0,stream>>>(dbc_f,0,0,64, PW(31),0,0,32,2, delta_f,0,0,1024, PF(32),1.f,3,32,1);
    k_mfma_gemm<<<dim3(16,32,1),256,0,stream>>>(dbc_b,0,0,64, PW(31),0,0,32,2, delta_b,0,0,1024, PF(32),1.f,3,32,1);
    k_scan1<<<dim3(16,32),256,0,stream>>>(delta_f,delta_b,xmc_f,xmc_b,dbc_f,dbc_b, PF(33), hend, Sdl);
    k_scan_carry<<<16,256,0,stream>>>(PF(33), hend, Sdl);
    k_scan2<<<dim3(16,32),256,0,stream>>>(delta_f,delta_b,xmc_f,xmc_b,dbc_f,dbc_b, PF(33), hend, y_f, y_b);
    k_gate<<<8192,256,0,stream>>>(y_f, xmc_f, xz, PF(34), 0);
    k_gate<<<8192,256,0,stream>>>(y_b, xmc_b, xz, PF(34), 1);
    k_mfma_gemm<<<dim3(8,32,1),256,0,stream>>>(y_f,0,0,1024, PW(35),0,0,1024,2, yproj_f,0,0,512, PF(36),1.f,0,1024,1);
    k_mfma_gemm<<<dim3(8,32,1),256,0,stream>>>(y_b,0,0,1024, PW(35),0,0,1024,2, yproj_b,0,0,512, PF(36),1.f,0,1024,1);
    k_combine_ln<<<2048,256,0,stream>>>(yproj_f, yproj_b, PF(20), PF(21), mbuf);
    k_mfma_gemm<<<dim3(32,32,1),256,0,stream>>>(mbuf,0,0,512, PW(22),0,0,512,2, ff1,0,0,2048, PF(23),1.f,2,512,1);
    k_mfma_gemm<<<dim3(8,32,1),256,0,stream>>>(ff1,0,0,2048, PW(24),0,0,2048,2, ffo,0,0,512, PF(25),1.f,0,2048,1);
    k_bimamba_final<<<2048,256,0,stream>>>(tgt_f, ffo, PF(12));

    // ---- final FFN ----
    k_mfma_gemm<<<dim3(32,32,1),256,0,stream>>>(tgt_f,0,0,512, PW(14),0,0,512,2, ff1,0,0,2048, PF(15),1.f,1,512,1);
    k_mfma_gemm<<<dim3(8,32,1),256,0,stream>>>(ff1,0,0,2048, PW(16),0,0,2048,2, t2,0,0,512, PF(17),1.f,0,2048,1);
    k_add_rmsnorm_out<<<2048,256,0,stream>>>(tgt_f, t2, PF(13), d_out, flag);
    #undef PF
    #undef PW
  }
}

// Round 4
// 758.234 us; speedup vs baseline: 3.2862x; 1.1956x over previous
//
#include <hip/hip_runtime.h>
#include <hip/hip_bf16.h>
#include <math.h>

#define L_SEQ 1024
#define BB 2
#define DD 512
#define HH 8
#define DFFN 2048
#define NSTATE 16
#define DI 1024
#define EPSF 1e-5f

typedef __hip_bfloat16 bf16;
typedef __attribute__((ext_vector_type(8))) short short8v;
typedef __attribute__((ext_vector_type(4))) short short4v;
typedef __attribute__((ext_vector_type(4))) float float4v;

__device__ __forceinline__ float bf2f(bf16 v){ return __bfloat162float(v); }
__device__ __forceinline__ bf16 f2bf(float v){ return __float2bfloat16(v); }
__device__ __forceinline__ short f2bfs(float v){
  bf16 t = __float2bfloat16(v);
  short s; __builtin_memcpy(&s, &t, 2);
  return s;
}

// ---------------- dtype detect ----------------
__global__ void k_detect(const unsigned int* __restrict__ w, int* __restrict__ flag){
  __shared__ int cnt;
  if (threadIdx.x==0) cnt = 0;
  __syncthreads();
  unsigned int x = w[threadIdx.x];
  unsigned int low = x & 0xffffu;
  int e = (int)((low >> 7) & 0xffu);
  int vote = (low==0u) || (e >= 110 && e <= 140);
  atomicAdd(&cnt, vote);
  __syncthreads();
  if (threadIdx.x==0) flag[0] = (cnt >= 128) ? 1 : 0;   // 1 = bf16 inputs, 0 = fp32
}

// ---------------- converts ----------------
struct CvtTabF { const void* src[25]; unsigned int off[26]; };
struct CvtTabW { const void* src[12]; unsigned int off[13]; };

__global__ __launch_bounds__(256) void k_cvt_f32(CvtTabF t, float* __restrict__ dst,
                                                 const int* __restrict__ flag, int total){
  const int isbf = flag[0];
  for (int g = blockIdx.x*256 + threadIdx.x; g < total; g += gridDim.x*256){
    int k = 0;
    while (t.off[k+1] <= (unsigned int)g) ++k;
    int e = g - (int)t.off[k];
    dst[g] = isbf ? bf2f(((const bf16*)t.src[k])[e]) : ((const float*)t.src[k])[e];
  }
}

__global__ __launch_bounds__(256) void k_cvt_b16(CvtTabW t, bf16* __restrict__ dst,
                                                 const int* __restrict__ flag, int total){
  const int isbf = flag[0];
  for (int g = blockIdx.x*256 + threadIdx.x; g < total; g += gridDim.x*256){
    int k = 0;
    while (t.off[k+1] <= (unsigned int)g) ++k;
    int e = g - (int)t.off[k];
    if (isbf) dst[g] = ((const bf16*)t.src[k])[e];
    else      dst[g] = f2bf(((const float*)t.src[k])[e]);
  }
}

// ---------------- batched-strided MFMA bf16 GEMM ----------------
// C[z][m][n] = act( scale * sum_k A[z][m][k]*B[z][n][k] + bias[n] )
// z = zb*H + zh. A fp32. B: cB=0 fp32 row-major n (k contig), cB=1 fp32 k-major, cB=2 bf16 (k contig)
__global__ __launch_bounds__(256) void k_mfma_gemm(
    const float* __restrict__ Ab, long long sAb, long long sAh, long long sAm,
    const void* __restrict__ Bb, long long sBb, long long sBh, long long sBrow, int cB,
    float* __restrict__ Cb, long long sCb, long long sCh, long long sCm,
    const float* __restrict__ bias, float scale, int act, int K, int H)
{
  __shared__ short As[64*40];
  __shared__ short Bs[64*40];
  const int tid = threadIdx.x;
  const int z = blockIdx.z; const int zb = z / H; const int zh = z % H;
  const int col0 = blockIdx.x << 6, m0 = blockIdx.y << 6;
  const float* Abase = Ab + zb*sAb + zh*sAh;
  const float* Bf = (const float*)Bb;
  const bf16* Bw = (const bf16*)Bb;
  const long long boff = zb*sBb + zh*sBh;
  float4v acc[4];
  #pragma unroll
  for (int i=0;i<4;++i) acc[i] = (float4v)(0.f);
  const int lane = tid & 63, w = tid >> 6;
  const int lr = lane & 15, quad = lane >> 4;

  for (int k0 = 0; k0 < K; k0 += 32){
    #pragma unroll
    for (int i=0;i<2;++i){
      int g = tid + i*256;
      int row = g >> 3, k4 = (g & 7) << 2;
      float4 v = *(const float4*)&Abase[(long long)(m0+row)*sAm + k0 + k4];
      short4v s4; s4.x=f2bfs(v.x); s4.y=f2bfs(v.y); s4.z=f2bfs(v.z); s4.w=f2bfs(v.w);
      *(short4v*)&As[row*40 + k4] = s4;
    }
    if (cB == 2){
      int row = tid >> 2, k8 = (tid & 3) << 3;
      short8v v = *(const short8v*)&Bw[boff + (long long)(col0+row)*sBrow + k0 + k8];
      *(short8v*)&Bs[row*40 + k8] = v;
    } else if (cB == 0){
      #pragma unroll
      for (int i=0;i<2;++i){
        int g = tid + i*256;
        int row = g >> 3, k4 = (g & 7) << 2;
        float4 v = *(const float4*)&Bf[boff + (long long)(col0+row)*sBrow + k0 + k4];
        short4v s4; s4.x=f2bfs(v.x); s4.y=f2bfs(v.y); s4.z=f2bfs(v.z); s4.w=f2bfs(v.w);
        *(short4v*)&Bs[row*40 + k4] = s4;
      }
    } else {
      #pragma unroll
      for (int i=0;i<2;++i){
        int g = tid + i*256;
        int k = g >> 4, n4 = (g & 15) << 2;
        float4 v = *(const float4*)&Bf[boff + (long long)(k0+k)*sBrow + col0 + n4];
        Bs[(n4+0)*40 + k] = f2bfs(v.x);
        Bs[(n4+1)*40 + k] = f2bfs(v.y);
        Bs[(n4+2)*40 + k] = f2bfs(v.z);
        Bs[(n4+3)*40 + k] = f2bfs(v.w);
      }
    }
    __syncthreads();
    short8v a = *(short8v*)&As[(w*16 + lr)*40 + quad*8];
    #pragma unroll
    for (int cb=0; cb<4; ++cb){
      short8v bfr = *(short8v*)&Bs[(cb*16 + lr)*40 + quad*8];
      acc[cb] = __builtin_amdgcn_mfma_f32_16x16x32_bf16(a, bfr, acc[cb], 0, 0, 0);
    }
    __syncthreads();
  }
  float* Crow = Cb + zb*sCb + zh*sCh;
  #pragma unroll
  for (int cb=0; cb<4; ++cb){
    #pragma unroll
    for (int r=0;r<4;++r){
      int m = m0 + w*16 + quad*4 + r;
      int n = col0 + cb*16 + lr;
      float v = acc[cb][r] * scale;
      if (bias) v += bias[n];
      if (act==1) v = fmaxf(v,0.f);
      else if (act==2) v = 0.5f*v*(1.f + erff(v*0.70710678118654752f));
      else if (act==3) v = fmaxf(v,0.f) + log1pf(__expf(-fabsf(v)));
      Crow[(long long)m*sCm + n] = v;
    }
  }
}

// ---------------- flash attention ----------------
// One block per (64-q tile, z=b*8+h). 256 thr = 4 waves, wave w owns q rows [w*16,w*16+16).
// Q/K/V strided fp32: addr = ((pos*BB+b)*ld + off + hoff + d). O fp32 [(q*BB+b)*512+hoff+d].
// If Pout: pass 2 recomputes S and writes normalized P (bf16) at Pout[z*1M + q*1024 + k].
__global__ __launch_bounds__(256) void k_flash(
    const float* __restrict__ Qb, int ldq, int qoff,
    const float* __restrict__ Kb, int ldk, int koff,
    const float* __restrict__ Vb, int ldv, int voff,
    float* __restrict__ O, bf16* __restrict__ Pout, float scale)
{
  __shared__ short Qs[64*40];
  __shared__ short Ks[64*40];
  __shared__ short Vs[64*40];   // transposed: Vs[d][kpos]
  __shared__ short Ps[64*40];
  const int tid = threadIdx.x;
  const int q0 = blockIdx.x << 6;
  const int z = blockIdx.y; const int b = z >> 3; const int hoff = (z & 7) << 6;
  const int lane = tid & 63, w = tid >> 6;
  const int lr = lane & 15, quad = lane >> 4;

  // stage Q once
  #pragma unroll
  for (int i=0;i<4;++i){
    int idx = tid + i*256;
    int row = idx >> 4, d4 = (idx & 15) << 2;
    float4 v = *(const float4*)&Qb[(size_t)((q0+row)*BB + b)*ldq + qoff + hoff + d4];
    short4v s4; s4.x=f2bfs(v.x); s4.y=f2bfs(v.y); s4.z=f2bfs(v.z); s4.w=f2bfs(v.w);
    *(short4v*)&Qs[row*40 + d4] = s4;
  }

  float m_r[4], l_r[4];
  #pragma unroll
  for (int r=0;r<4;++r){ m_r[r] = -1e30f; l_r[r] = 0.f; }
  float4v acc_o[4];
  #pragma unroll
  for (int cb=0;cb<4;++cb) acc_o[cb] = (float4v)(0.f);

  // prefetch K/V tile 0 into regs
  float4 kr[4], vr[4];
  #pragma unroll
  for (int i=0;i<4;++i){
    int idx = tid + i*256;
    int row = idx >> 4, d4 = (idx & 15) << 2;
    kr[i] = *(const float4*)&Kb[(size_t)(row*BB + b)*ldk + koff + hoff + d4];
    vr[i] = *(const float4*)&Vb[(size_t)(row*BB + b)*ldv + voff + hoff + d4];
  }

  for (int kt=0; kt<16; ++kt){
    __syncthreads();     // prior iter done reading Ks/Vs/Ps
    #pragma unroll
    for (int i=0;i<4;++i){
      int idx = tid + i*256;
      int row = idx >> 4, d4 = (idx & 15) << 2;   // row = kpos
      short4v s4; s4.x=f2bfs(kr[i].x); s4.y=f2bfs(kr[i].y); s4.z=f2bfs(kr[i].z); s4.w=f2bfs(kr[i].w);
      *(short4v*)&Ks[row*40 + d4] = s4;
      Vs[(d4+0)*40 + row] = f2bfs(vr[i].x);
      Vs[(d4+1)*40 + row] = f2bfs(vr[i].y);
      Vs[(d4+2)*40 + row] = f2bfs(vr[i].z);
      Vs[(d4+3)*40 + row] = f2bfs(vr[i].w);
    }
    if (kt < 15){
      #pragma unroll
      for (int i=0;i<4;++i){
        int idx = tid + i*256;
        int row = ((kt+1)<<6) + (idx >> 4); int d4 = (idx & 15) << 2;
        kr[i] = *(const float4*)&Kb[(size_t)(row*BB + b)*ldk + koff + hoff + d4];
        vr[i] = *(const float4*)&Vb[(size_t)(row*BB + b)*ldv + voff + hoff + d4];
      }
    }
    __syncthreads();
    // S = scale * Q K^T
    short8v a0 = *(short8v*)&Qs[(w*16+lr)*40 + quad*8];
    short8v a1 = *(short8v*)&Qs[(w*16+lr)*40 + quad*8 + 32];
    float4v s[4];
    #pragma unroll
    for (int cb=0;cb<4;++cb){
      short8v b0 = *(short8v*)&Ks[(cb*16+lr)*40 + quad*8];
      short8v b1 = *(short8v*)&Ks[(cb*16+lr)*40 + quad*8 + 32];
      float4v t = __builtin_amdgcn_mfma_f32_16x16x32_bf16(a0, b0, (float4v)(0.f), 0,0,0);
      s[cb] = __builtin_amdgcn_mfma_f32_16x16x32_bf16(a1, b1, t, 0,0,0);
    }
    #pragma unroll
    for (int cb=0;cb<4;++cb)
      #pragma unroll
      for (int r=0;r<4;++r) s[cb][r] *= scale;
    // online softmax (rows quad*4+r; cols across lr and cb)
    float al[4];
    #pragma unroll
    for (int r=0;r<4;++r){
      float mx = fmaxf(fmaxf(s[0][r],s[1][r]),fmaxf(s[2][r],s[3][r]));
      #pragma unroll
      for (int ofs=1; ofs<16; ofs<<=1) mx = fmaxf(mx, __shfl_xor(mx, ofs));
      float mnew = fmaxf(m_r[r], mx);
      al[r] = __expf(m_r[r] - mnew);
      float sum = 0.f;
      #pragma unroll
      for (int cb=0;cb<4;++cb){
        float p = __expf(s[cb][r] - mnew);
        s[cb][r] = p;
        sum += p;
      }
      #pragma unroll
      for (int ofs=1; ofs<16; ofs<<=1) sum += __shfl_xor(sum, ofs);
      l_r[r] = l_r[r]*al[r] + sum;
      m_r[r] = mnew;
    }
    // rescale O, store P in A-operand layout
    #pragma unroll
    for (int cb=0;cb<4;++cb)
      #pragma unroll
      for (int r=0;r<4;++r){
        acc_o[cb][r] *= al[r];
        Ps[(w*16 + quad*4 + r)*40 + cb*16 + lr] = f2bfs(s[cb][r]);
      }
    __syncthreads();
    // O += P V
    short8v p0 = *(short8v*)&Ps[(w*16+lr)*40 + quad*8];
    short8v p1 = *(short8v*)&Ps[(w*16+lr)*40 + quad*8 + 32];
    #pragma unroll
    for (int cb=0;cb<4;++cb){
      short8v v0 = *(short8v*)&Vs[(cb*16+lr)*40 + quad*8];
      short8v v1 = *(short8v*)&Vs[(cb*16+lr)*40 + quad*8 + 32];
      acc_o[cb] = __builtin_amdgcn_mfma_f32_16x16x32_bf16(p0, v0, acc_o[cb], 0,0,0);
      acc_o[cb] = __builtin_amdgcn_mfma_f32_16x16x32_bf16(p1, v1, acc_o[cb], 0,0,0);
    }
  }
  float linv[4];
  #pragma unroll
  for (int r=0;r<4;++r) linv[r] = 1.f/l_r[r];
  #pragma unroll
  for (int cb=0;cb<4;++cb)
    #pragma unroll
    for (int r=0;r<4;++r){
      int q = q0 + w*16 + quad*4 + r;
      O[(size_t)(q*BB + b)*512 + hoff + cb*16 + lr] = acc_o[cb][r]*linv[r];
    }

  if (Pout){
    bf16* Pz = Pout + (size_t)z*(1u<<20);
    for (int kt=0; kt<16; ++kt){
      __syncthreads();
      #pragma unroll
      for (int i=0;i<4;++i){
        int idx = tid + i*256;
        int row = (idx >> 4), d4 = (idx & 15) << 2;
        float4 v = *(const float4*)&Kb[(size_t)((((kt<<6)+row))*BB + b)*ldk + koff + hoff + d4];
        short4v s4; s4.x=f2bfs(v.x); s4.y=f2bfs(v.y); s4.z=f2bfs(v.z); s4.w=f2bfs(v.w);
        *(short4v*)&Ks[row*40 + d4] = s4;
      }
      __syncthreads();
      short8v a0 = *(short8v*)&Qs[(w*16+lr)*40 + quad*8];
      short8v a1 = *(short8v*)&Qs[(w*16+lr)*40 + quad*8 + 32];
      #pragma unroll
      for (int cb=0;cb<4;++cb){
        short8v b0 = *(short8v*)&Ks[(cb*16+lr)*40 + quad*8];
        short8v b1 = *(short8v*)&Ks[(cb*16+lr)*40 + quad*8 + 32];
        float4v t = __builtin_amdgcn_mfma_f32_16x16x32_bf16(a0, b0, (float4v)(0.f), 0,0,0);
        t = __builtin_amdgcn_mfma_f32_16x16x32_bf16(a1, b1, t, 0,0,0);
        #pragma unroll
        for (int r=0;r<4;++r){
          float p = __expf(t[r]*scale - m_r[r]) * linv[r];
          Pz[(size_t)(q0 + w*16 + quad*4 + r)*1024 + (kt<<6) + cb*16 + lr] = f2bf(p);
        }
      }
    }
  }
}

// ---------------- mean over heads (bf16 P) -> output ----------------
__global__ __launch_bounds__(256) void k_attn_mean_b(const bf16* __restrict__ P, void* __restrict__ out,
                                                     const int* __restrict__ flag){
  int idx = blockIdx.x*256 + threadIdx.x;  // 2M
  int b = idx >> 20; int rem = idx & ((1<<20)-1);
  const bf16* p = P + (size_t)b*HH*(1u<<20) + rem;
  float s = 0.f;
  #pragma unroll
  for (int h=0;h<HH;++h) s += bf2f(p[(size_t)h*(1u<<20)]);
  s *= 0.125f;
  size_t o = (size_t)(1u<<20) + (size_t)idx;
  if (flag[0]) ((bf16*)out)[o] = f2bf(s);
  else         ((float*)out)[o] = s;
}

// ---------------- norms / elementwise ----------------
__global__ __launch_bounds__(256) void k_add_rmsnorm(float* __restrict__ x, const float* __restrict__ t2, const float* __restrict__ w){
  int row = blockIdx.x; size_t base = (size_t)row*DD;
  int tid = threadIdx.x;
  float v0 = x[base+tid] + t2[base+tid];
  float v1 = x[base+tid+256] + t2[base+tid+256];
  __shared__ float red[256];
  red[tid] = v0*v0 + v1*v1; __syncthreads();
  for (int s=128;s>0;s>>=1){ if(tid<s) red[tid]+=red[tid+s]; __syncthreads(); }
  float rms = rsqrtf(red[0]*(1.f/DD) + EPSF);
  x[base+tid]     = v0 * w[tid]     * rms;
  x[base+tid+256] = v1 * w[tid+256] * rms;
}

__global__ __launch_bounds__(256) void k_add_rmsnorm_out(const float* __restrict__ x, const float* __restrict__ t2,
                                                         const float* __restrict__ w, void* __restrict__ out,
                                                         const int* __restrict__ flag){
  int row = blockIdx.x; size_t base = (size_t)row*DD;
  int tid = threadIdx.x;
  float v0 = x[base+tid] + t2[base+tid];
  float v1 = x[base+tid+256] + t2[base+tid+256];
  __shared__ float red[256];
  red[tid] = v0*v0 + v1*v1; __syncthreads();
  for (int s=128;s>0;s>>=1){ if(tid<s) red[tid]+=red[tid+s]; __syncthreads(); }
  float rms = rsqrtf(red[0]*(1.f/DD) + EPSF);
  float o0 = v0 * w[tid]     * rms;
  float o1 = v1 * w[tid+256] * rms;
  if (flag[0]){ ((bf16*)out)[base+tid] = f2bf(o0); ((bf16*)out)[base+tid+256] = f2bf(o1); }
  else        { ((float*)out)[base+tid] = o0;      ((float*)out)[base+tid+256] = o1; }
}

__global__ __launch_bounds__(256) void k_trans_layernorm(const float* __restrict__ tgt, const float* __restrict__ w, const float* __restrict__ bias, float* __restrict__ xn){
  int r = blockIdx.x;        // b*L + l
  int b = r >> 10, l = r & 1023;
  size_t src = ((size_t)l*BB + b)*DD;
  int tid = threadIdx.x;
  float v0 = tgt[src+tid], v1 = tgt[src+tid+256];
  __shared__ float red[256];
  red[tid] = v0 + v1; __syncthreads();
  for (int s=128;s>0;s>>=1){ if(tid<s) red[tid]+=red[tid+s]; __syncthreads(); }
  float mean = red[0]*(1.f/DD);
  __syncthreads();
  red[tid] = v0*v0 + v1*v1; __syncthreads();
  for (int s=128;s>0;s>>=1){ if(tid<s) red[tid]+=red[tid+s]; __syncthreads(); }
  float var = red[0]*(1.f/DD) - mean*mean;
  float rstd = rsqrtf(var + EPSF);
  size_t dst = (size_t)r*DD;
  xn[dst+tid]     = (v0-mean)*rstd*w[tid]     + bias[tid];
  xn[dst+tid+256] = (v1-mean)*rstd*w[tid+256] + bias[tid+256];
}

__global__ __launch_bounds__(256) void k_combine_ln(const float* __restrict__ yf, const float* __restrict__ yb, const float* __restrict__ w, const float* __restrict__ bias, float* __restrict__ mo){
  int r = blockIdx.x; int b = r>>10, l = r&1023;
  size_t rf = (size_t)r*DD;
  size_t rb = ((size_t)(b<<10) + (1023 - l))*DD;
  int tid = threadIdx.x;
  float v0 = yf[rf+tid]     + yb[rb+tid];
  float v1 = yf[rf+tid+256] + yb[rb+tid+256];
  __shared__ float red[256];
  red[tid] = v0 + v1; __syncthreads();
  for (int s=128;s>0;s>>=1){ if(tid<s) red[tid]+=red[tid+s]; __syncthreads(); }
  float mean = red[0]*(1.f/DD);
  __syncthreads();
  red[tid] = v0*v0 + v1*v1; __syncthreads();
  for (int s=128;s>0;s>>=1){ if(tid<s) red[tid]+=red[tid+s]; __syncthreads(); }
  float var = red[0]*(1.f/DD) - mean*mean;
  float rstd = rsqrtf(var + EPSF);
  mo[rf+tid]     = (v0-mean)*rstd*w[tid]     + bias[tid];
  mo[rf+tid+256] = (v1-mean)*rstd*w[tid+256] + bias[tid+256];
}

__global__ __launch_bounds__(256) void k_bimamba_final(float* __restrict__ tgt, const float* __restrict__ ffo, const float* __restrict__ w){
  int r = blockIdx.x; int b = r>>10, l = r&1023;
  size_t t = ((size_t)l*BB + b)*DD;
  size_t f = (size_t)r*DD;
  int tid = threadIdx.x;
  float v0 = 2.f*tgt[t+tid]     + ffo[f+tid];
  float v1 = 2.f*tgt[t+tid+256] + ffo[f+tid+256];
  __shared__ float red[256];
  red[tid] = v0*v0 + v1*v1; __syncthreads();
  for (int s=128;s>0;s>>=1){ if(tid<s) red[tid]+=red[tid+s]; __syncthreads(); }
  float rms = rsqrtf(red[0]*(1.f/DD) + EPSF);
  tgt[t+tid]     = v0 * w[tid]     * rms;
  tgt[t+tid+256] = v1 * w[tid+256] * rms;
}

// ---------------- causal depthwise conv + silu (both directions via blockIdx.y) ----------------
__global__ __launch_bounds__(256) void k_conv_silu(const float* __restrict__ xz, const float* __restrict__ cw, const float* __restrict__ cb, float* __restrict__ xmc){
  int rev = blockIdx.y;
  int idx = blockIdx.x*256 + threadIdx.x;  // 2M
  int c = idx & 1023;
  int l = (idx >> 10) & 1023;
  int b = idx >> 20;
  float acc = cb[c];
  float w4[4];
  #pragma unroll
  for (int j=0;j<4;++j) w4[j] = cw[(c<<2)+j];
  #pragma unroll
  for (int j=0;j<4;++j){
    int t = l - 3 + j;
    if (t >= 0){
      int src = rev ? (1023 - t) : t;
      acc = fmaf(w4[j], xz[((size_t)(b<<10) + src)*2048 + c], acc);
    }
  }
  xmc[(size_t)rev*(2u<<20) + idx] = acc / (1.f + __expf(-acc));
}

// ---------------- chunked selective scan ----------------
__global__ __launch_bounds__(256) void k_scan1(
    const float* __restrict__ delta_f, const float* __restrict__ delta_b,
    const float* __restrict__ xmc_f,  const float* __restrict__ xmc_b,
    const float* __restrict__ dbc_f,  const float* __restrict__ dbc_b,
    const float* __restrict__ Alog,
    float* __restrict__ hend, float* __restrict__ Sdl)
{
  int ch = blockIdx.x*256 + threadIdx.x;
  int c = blockIdx.y;
  int dir = ch >> 11, b = (ch >> 10) & 1, d = ch & 1023;
  const float* delta = dir ? delta_b : delta_f;
  const float* xmc   = dir ? xmc_b   : xmc_f;
  const float* dbc   = dir ? dbc_b   : dbc_f;
  float Av[NSTATE];
  #pragma unroll
  for (int n=0;n<NSTATE;++n) Av[n] = -__expf(Alog[d*NSTATE+n]);
  float h[NSTATE];
  #pragma unroll
  for (int n=0;n<NSTATE;++n) h[n]=0.f;
  float S = 0.f;
  int r0 = b*1024 + c*32;
  for (int t=0;t<32;++t){
    int r = r0 + t;
    float dl = delta[((size_t)r<<10) + d];
    float x  = xmc[((size_t)r<<10) + d];
    const float4* bp = (const float4*)(dbc + (size_t)r*64 + 32);
    float Bv[NSTATE];
    ((float4*)Bv)[0]=bp[0]; ((float4*)Bv)[1]=bp[1]; ((float4*)Bv)[2]=bp[2]; ((float4*)Bv)[3]=bp[3];
    S += dl;
    float dx = dl*x;
    #pragma unroll
    for (int n=0;n<NSTATE;++n){
      float dA = __expf(dl*Av[n]);
      h[n] = fmaf(dA, h[n], dx*Bv[n]);
    }
  }
  size_t base = ((size_t)c*4096 + ch)*16;
  #pragma unroll
  for (int n=0;n<NSTATE;++n) hend[base+n] = h[n];
  Sdl[c*4096 + ch] = S;
}

__global__ __launch_bounds__(256) void k_scan_carry(const float* __restrict__ Alog,
                                                    float* __restrict__ hh, const float* __restrict__ Sdl)
{
  int ch = blockIdx.x*256 + threadIdx.x;
  int d = ch & 1023;
  float Av[NSTATE];
  #pragma unroll
  for (int n=0;n<NSTATE;++n) Av[n] = -__expf(Alog[d*NSTATE+n]);
  float h[NSTATE];
  #pragma unroll
  for (int n=0;n<NSTATE;++n) h[n]=0.f;
  for (int c=0;c<32;++c){
    size_t base = ((size_t)c*4096 + ch)*16;
    float S = Sdl[c*4096 + ch];
    float he[NSTATE];
    #pragma unroll
    for (int n=0;n<NSTATE;++n) he[n] = hh[base+n];
    #pragma unroll
    for (int n=0;n<NSTATE;++n) hh[base+n] = h[n];
    #pragma unroll
    for (int n=0;n<NSTATE;++n) h[n] = fmaf(__expf(Av[n]*S), h[n], he[n]);
  }
}

__global__ __launch_bounds__(256) void k_scan2(
    const float* __restrict__ delta_f, const float* __restrict__ delta_b,
    const float* __restrict__ xmc_f,  const float* __restrict__ xmc_b,
    const float* __restrict__ dbc_f,  const float* __restrict__ dbc_b,
    const float* __restrict__ Alog,   const float* __restrict__ hin,
    float* __restrict__ y_f, float* __restrict__ y_b)
{
  int ch = blockIdx.x*256 + threadIdx.x;
  int c = blockIdx.y;
  int dir = ch >> 11, b = (ch >> 10) & 1, d = ch & 1023;
  const float* delta = dir ? delta_b : delta_f;
  const float* xmc   = dir ? xmc_b   : xmc_f;
  const float* dbc   = dir ? dbc_b   : dbc_f;
  float* y           = dir ? y_b     : y_f;
  float Av[NSTATE];
  #pragma unroll
  for (int n=0;n<NSTATE;++n) Av[n] = -__expf(Alog[d*NSTATE+n]);
  float h[NSTATE];
  size_t cbase = ((size_t)c*4096 + ch)*16;
  #pragma unroll
  for (int n=0;n<NSTATE;++n) h[n] = hin[cbase+n];
  int r0 = b*1024 + c*32;
  for (int t=0;t<32;++t){
    int r = r0 + t;
    float dl = delta[((size_t)r<<10) + d];
    float x  = xmc[((size_t)r<<10) + d];
    const float4* bp = (const float4*)(dbc + (size_t)r*64 + 32);
    float Bv[NSTATE], Cv[NSTATE];
    ((float4*)Bv)[0]=bp[0]; ((float4*)Bv)[1]=bp[1]; ((float4*)Bv)[2]=bp[2]; ((float4*)Bv)[3]=bp[3];
    ((float4*)Cv)[0]=bp[4]; ((float4*)Cv)[1]=bp[5]; ((float4*)Cv)[2]=bp[6]; ((float4*)Cv)[3]=bp[7];
    float dx = dl*x;
    float acc = 0.f;
    #pragma unroll
    for (int n=0;n<NSTATE;++n){
      float dA = __expf(dl*Av[n]);
      h[n] = fmaf(dA, h[n], dx*Bv[n]);
      acc = fmaf(h[n], Cv[n], acc);
    }
    y[((size_t)r<<10) + d] = acc;
  }
}

// ---------------- y = (y + Dp*xmc) * silu(z) (both directions via blockIdx.y) ----------------
__global__ __launch_bounds__(256) void k_gate(float* __restrict__ y, const float* __restrict__ xmc, const float* __restrict__ xz, const float* __restrict__ Dp){
  int rev = blockIdx.y;
  int idx = blockIdx.x*256 + threadIdx.x;  // 2M
  int c = idx & 1023;
  int l = (idx >> 10) & 1023;
  int b = idx >> 20;
  int src = rev ? (1023 - l) : l;
  float z = xz[((size_t)(b<<10)+src)*2048 + 1024 + c];
  float s = z / (1.f + __expf(-z));
  size_t o = (size_t)rev*(2u<<20) + idx;
  y[o] = (y[o] + Dp[c]*xmc[o]) * s;
}

extern "C" void kernel_launch(void* const* d_in, const int* in_sizes, int n_in,
                              void* d_out, int out_size, void* d_ws, size_t ws_size,
                              hipStream_t stream)
{
  if (n_in < 37) return;
  static const unsigned int SZ[37] = {
    1048576,1048576,786432,1536,262144,512,786432,1536,262144,512,
    512,512,512,512,1048576,2048,1048576,512,512,512,
    512,512,1048576,2048,1048576,512,1048576,2048,4096,1024,
    65536,32768,1024,16384,1024,524288,512
  };
  static const unsigned char ISW[37] = {
    0,0,1,0,1,0,1,0,1,0, 0,0,0,0,1,0,1,0,0,0,
    0,0,1,0,1,0,1,0,0,0, 1,1,0,0,0,1,0
  };
  const long long MF = 1u<<20;
  if (ws_size < (size_t)(32*MF)*sizeof(float)) return;   // 128 MB

  float* ws = (float*)d_ws;
  float* inF = ws;                       // fp32 params arena  [0, 3MF)
  bf16*  inB = (bf16*)(ws + 3*MF);       // bf16 weight arena  [3MF, 7MF)
  float* t2    = ws + 7*MF;
  float* mbuf  = ws + 8*MF;
  float* proj  = ws + 9*MF;              // 3MF
  float* big   = ws + 12*MF;             // 16MF
  float* ff1   = ws + 28*MF;             // 4MF

  CvtTabF tf; CvtTabW tb;
  unsigned int fOff[37], bOff[37];
  {
    int nf=0, nb=0; unsigned int of=0, ob=0;
    for (int i=0;i<37;++i){
      if (ISW[i]){ tb.src[nb]=d_in[i]; tb.off[nb]=ob; bOff[i]=ob; ob+=SZ[i]; ++nb; }
      else       { tf.src[nf]=d_in[i]; tf.off[nf]=of; fOff[i]=of; of+=SZ[i]; ++nf; }
    }
    tf.off[25]=of; tb.off[12]=ob;
    int* flag = (int*)(ws + 3*MF - 16);

    #define PF(i) (inF + fOff[i])
    #define PW(i) (inB + bOff[i])

    float* tgt_f = PF(0);
    float* mem_f = PF(1);
    float* qkv     = proj;
    float* attno   = mbuf;
    float* xn      = t2;
    float* xz      = big;
    float* xmc_f   = big + 4*MF;
    float* delta_f = big + 8*MF;
    float* delta_b = big + 10*MF;
    float* y_f     = big + 12*MF;
    float* dbc_f   = proj;
    float* dbc_b   = proj + 131072;
    float* yproj_f = proj + 1*MF;
    float* yproj_b = proj + 2*MF;
    float* ffo     = mem_f;
    float* hend    = ff1;                // 2MF
    float* Sdl     = ff1 + 2*MF;         // 128K
    float* xmc_b   = xmc_f + 2*MF;
    float* y_b     = y_f + 2*MF;

    k_detect<<<1,256,0,stream>>>((const unsigned int*)d_in[0], flag);
    k_cvt_f32<<<2048,256,0,stream>>>(tf, inF, flag, (int)of);
    k_cvt_b16<<<4096,256,0,stream>>>(tb, inB, flag, (int)ob);

    // ---- self attention ----
    k_mfma_gemm<<<dim3(24,32,1),256,0,stream>>>(tgt_f,0,0,512, PW(2),0,0,512,2, qkv,0,0,1536, PF(3),1.f,0,512,1);
    k_flash<<<dim3(16,16),256,0,stream>>>(qkv,1536,0, qkv,1536,512, qkv,1536,1024, attno, nullptr, 0.125f);
    k_mfma_gemm<<<dim3(8,32,1),256,0,stream>>>(attno,0,0,512, PW(4),0,0,512,2, t2,0,0,512, PF(5),1.f,0,512,1);
    k_add_rmsnorm<<<2048,256,0,stream>>>(tgt_f, t2, PF(10));

    // ---- cross attention ----
    k_mfma_gemm<<<dim3(8,32,1),256,0,stream>>>(tgt_f,0,0,512, PW(6),0,0,512,2, proj,0,0,512, PF(7),1.f,0,512,1);
    k_mfma_gemm<<<dim3(16,32,1),256,0,stream>>>(mem_f,0,0,512, PW(6)+(size_t)512*512,0,0,512,2, proj+MF,0,0,1024, PF(7)+512,1.f,0,512,1);
    k_flash<<<dim3(16,16),256,0,stream>>>(proj,512,0, proj+MF,1024,0, proj+MF,1024,512, attno, (bf16*)big, 0.125f);
    k_attn_mean_b<<<8192,256,0,stream>>>((const bf16*)big, d_out, flag);
    k_mfma_gemm<<<dim3(8,32,1),256,0,stream>>>(attno,0,0,512, PW(8),0,0,512,2, t2,0,0,512, PF(9),1.f,0,512,1);
    k_add_rmsnorm<<<2048,256,0,stream>>>(tgt_f, t2, PF(11));

    // ---- bimamba ----
    k_trans_layernorm<<<2048,256,0,stream>>>(tgt_f, PF(18), PF(19), xn);
    k_mfma_gemm<<<dim3(32,32,1),256,0,stream>>>(xn,0,0,512, PW(26),0,0,512,2, xz,0,0,2048, PF(27),1.f,0,512,1);
    k_conv_silu<<<dim3(8192,2),256,0,stream>>>(xz, PF(28), PF(29), xmc_f);
    k_mfma_gemm<<<dim3(1,32,2),256,0,stream>>>(xmc_f,2*MF,0,1024, PW(30),0,0,1024,2, dbc_f,131072,0,64, nullptr,1.f,0,1024,1);
    k_mfma_gemm<<<dim3(16,32,2),256,0,stream>>>(dbc_f,131072,0,64, PW(31),0,0,32,2, delta_f,2*MF,0,1024, PF(32),1.f,3,32,1);
    k_scan1<<<dim3(16,32),256,0,stream>>>(delta_f,delta_b,xmc_f,xmc_b,dbc_f,dbc_b, PF(33), hend, Sdl);
    k_scan_carry<<<16,256,0,stream>>>(PF(33), hend, Sdl);
    k_scan2<<<dim3(16,32),256,0,stream>>>(delta_f,delta_b,xmc_f,xmc_b,dbc_f,dbc_b, PF(33), hend, y_f, y_b);
    k_gate<<<dim3(8192,2),256,0,stream>>>(y_f, xmc_f, xz, PF(34));
    k_mfma_gemm<<<dim3(8,32,2),256,0,stream>>>(y_f,2*MF,0,1024, PW(35),0,0,1024,2, yproj_f,1*MF,0,512, PF(36),1.f,0,1024,1);
    k_combine_ln<<<2048,256,0,stream>>>(yproj_f, yproj_b, PF(20), PF(21), mbuf);
    k_mfma_gemm<<<dim3(32,32,1),256,0,stream>>>(mbuf,0,0,512, PW(22),0,0,512,2, ff1,0,0,2048, PF(23),1.f,2,512,1);
    k_mfma_gemm<<<dim3(8,32,1),256,0,stream>>>(ff1,0,0,2048, PW(24),0,0,2048,2, ffo,0,0,512, PF(25),1.f,0,2048,1);
    k_bimamba_final<<<2048,256,0,stream>>>(tgt_f, ffo, PF(12));

    // ---- final FFN ----
    k_mfma_gemm<<<dim3(32,32,1),256,0,stream>>>(tgt_f,0,0,512, PW(14),0,0,512,2, ff1,0,0,2048, PF(15),1.f,1,512,1);
    k_mfma_gemm<<<dim3(8,32,1),256,0,stream>>>(ff1,0,0,2048, PW(16),0,0,2048,2, t2,0,0,512, PF(17),1.f,0,2048,1);
    k_add_rmsnorm_out<<<2048,256,0,stream>>>(tgt_f, t2, PF(13), d_out, flag);
    #undef PF
    #undef PW
  }
}

// Round 5
// 693.925 us; speedup vs baseline: 3.5908x; 1.0927x over previous
//
#include <hip/hip_runtime.h>
#include <hip/hip_bf16.h>
#include <math.h>

#define L_SEQ 1024
#define BB 2
#define DD 512
#define HH 8
#define DFFN 2048
#define NSTATE 16
#define DI 1024
#define EPSF 1e-5f

typedef __hip_bfloat16 bf16;
typedef __attribute__((ext_vector_type(8))) short short8v;
typedef __attribute__((ext_vector_type(4))) short short4v;
typedef __attribute__((ext_vector_type(4))) float float4v;

__device__ __forceinline__ float bf2f(bf16 v){ return __bfloat162float(v); }
__device__ __forceinline__ bf16 f2bf(float v){ return __float2bfloat16(v); }
__device__ __forceinline__ short f2bfs(float v){
  bf16 t = __float2bfloat16(v);
  short s; __builtin_memcpy(&s, &t, 2);
  return s;
}

// ---------------- dtype detect ----------------
__global__ void k_detect(const unsigned int* __restrict__ w, int* __restrict__ flag){
  __shared__ int cnt;
  if (threadIdx.x==0) cnt = 0;
  __syncthreads();
  unsigned int x = w[threadIdx.x];
  unsigned int low = x & 0xffffu;
  int e = (int)((low >> 7) & 0xffu);
  int vote = (low==0u) || (e >= 110 && e <= 140);
  atomicAdd(&cnt, vote);
  __syncthreads();
  if (threadIdx.x==0) flag[0] = (cnt >= 128) ? 1 : 0;   // 1 = bf16 inputs, 0 = fp32
}

// ---------------- converts ----------------
struct CvtTabF { const void* src[25]; unsigned int off[26]; };
struct CvtTabW { const void* src[12]; unsigned int off[13]; };

__global__ __launch_bounds__(256) void k_cvt_f32(CvtTabF t, float* __restrict__ dst,
                                                 const int* __restrict__ flag, int total){
  const int isbf = flag[0];
  for (int g = blockIdx.x*256 + threadIdx.x; g < total; g += gridDim.x*256){
    int k = 0;
    while (t.off[k+1] <= (unsigned int)g) ++k;
    int e = g - (int)t.off[k];
    dst[g] = isbf ? bf2f(((const bf16*)t.src[k])[e]) : ((const float*)t.src[k])[e];
  }
}

__global__ __launch_bounds__(256) void k_cvt_b16(CvtTabW t, bf16* __restrict__ dst,
                                                 const int* __restrict__ flag, int total){
  const int isbf = flag[0];
  for (int g = blockIdx.x*256 + threadIdx.x; g < total; g += gridDim.x*256){
    int k = 0;
    while (t.off[k+1] <= (unsigned int)g) ++k;
    int e = g - (int)t.off[k];
    if (isbf) dst[g] = ((const bf16*)t.src[k])[e];
    else      dst[g] = f2bf(((const float*)t.src[k])[e]);
  }
}

// ---------------- batched-strided MFMA bf16 GEMM ----------------
// C[z][m][n] = act( scale * sum_k A[z][m][k]*B[z][n][k] + bias[n] ), z = zb*H+zh
// cA: 0 = A fp32, 1 = A bf16 (k-contig). cB: 0 fp32 k-contig, 1 fp32 k-major, 2 bf16 k-contig.
// outBf: 1 -> C bf16, 0 -> C fp32. Strides in elements of respective dtype.
// XCD swizzle: when gz==1 && gy%8==0, all col-blocks of a row-strip map to one XCD.
__global__ __launch_bounds__(256) void k_mfma_gemm(
    const void* __restrict__ Ab, int cA, long long sAb, long long sAh, long long sAm,
    const void* __restrict__ Bb, long long sBb, long long sBh, long long sBrow, int cB,
    void* __restrict__ Cb, int outBf, long long sCb, long long sCh, long long sCm,
    const float* __restrict__ bias, float scale, int act, int K, int H)
{
  __shared__ short As[64*40];
  __shared__ short Bs[64*40];
  const int tid = threadIdx.x;
  int bx = blockIdx.x, by = blockIdx.y;
  if (gridDim.z == 1 && (gridDim.y & 7) == 0){
    int gx = gridDim.x;
    int lin = by*gx + bx;
    int xcd = lin & 7, i = lin >> 3;
    by = xcd*(gridDim.y >> 3) + i / gx;
    bx = i % gx;
  }
  const int z = blockIdx.z; const int zb = z / H; const int zh = z % H;
  const int col0 = bx << 6, m0 = by << 6;
  const float* Af = (const float*)Ab;
  const bf16*  Aw = (const bf16*)Ab;
  const long long aoff = zb*sAb + zh*sAh;
  const float* Bf = (const float*)Bb;
  const bf16* Bw = (const bf16*)Bb;
  const long long boff = zb*sBb + zh*sBh;
  float4v acc[4];
  #pragma unroll
  for (int i=0;i<4;++i) acc[i] = (float4v)(0.f);
  const int lane = tid & 63, w = tid >> 6;
  const int lr = lane & 15, quad = lane >> 4;

  for (int k0 = 0; k0 < K; k0 += 32){
    if (cA == 1){
      int row = tid >> 2, k8 = (tid & 3) << 3;
      short8v v = *(const short8v*)&Aw[aoff + (long long)(m0+row)*sAm + k0 + k8];
      *(short8v*)&As[row*40 + k8] = v;
    } else {
      #pragma unroll
      for (int i=0;i<2;++i){
        int g = tid + i*256;
        int row = g >> 3, k4 = (g & 7) << 2;
        float4 v = *(const float4*)&Af[aoff + (long long)(m0+row)*sAm + k0 + k4];
        short4v s4; s4.x=f2bfs(v.x); s4.y=f2bfs(v.y); s4.z=f2bfs(v.z); s4.w=f2bfs(v.w);
        *(short4v*)&As[row*40 + k4] = s4;
      }
    }
    if (cB == 2){
      int row = tid >> 2, k8 = (tid & 3) << 3;
      short8v v = *(const short8v*)&Bw[boff + (long long)(col0+row)*sBrow + k0 + k8];
      *(short8v*)&Bs[row*40 + k8] = v;
    } else if (cB == 0){
      #pragma unroll
      for (int i=0;i<2;++i){
        int g = tid + i*256;
        int row = g >> 3, k4 = (g & 7) << 2;
        float4 v = *(const float4*)&Bf[boff + (long long)(col0+row)*sBrow + k0 + k4];
        short4v s4; s4.x=f2bfs(v.x); s4.y=f2bfs(v.y); s4.z=f2bfs(v.z); s4.w=f2bfs(v.w);
        *(short4v*)&Bs[row*40 + k4] = s4;
      }
    } else {
      #pragma unroll
      for (int i=0;i<2;++i){
        int g = tid + i*256;
        int k = g >> 4, n4 = (g & 15) << 2;
        float4 v = *(const float4*)&Bf[boff + (long long)(k0+k)*sBrow + col0 + n4];
        Bs[(n4+0)*40 + k] = f2bfs(v.x);
        Bs[(n4+1)*40 + k] = f2bfs(v.y);
        Bs[(n4+2)*40 + k] = f2bfs(v.z);
        Bs[(n4+3)*40 + k] = f2bfs(v.w);
      }
    }
    __syncthreads();
    short8v a = *(short8v*)&As[(w*16 + lr)*40 + quad*8];
    #pragma unroll
    for (int cb=0; cb<4; ++cb){
      short8v bfr = *(short8v*)&Bs[(cb*16 + lr)*40 + quad*8];
      acc[cb] = __builtin_amdgcn_mfma_f32_16x16x32_bf16(a, bfr, acc[cb], 0, 0, 0);
    }
    __syncthreads();
  }
  #pragma unroll
  for (int cb=0; cb<4; ++cb){
    #pragma unroll
    for (int r=0;r<4;++r){
      int m = m0 + w*16 + quad*4 + r;
      int n = col0 + cb*16 + lr;
      float v = acc[cb][r] * scale;
      if (bias) v += bias[n];
      if (act==1) v = fmaxf(v,0.f);
      else if (act==2) v = 0.5f*v*(1.f + erff(v*0.70710678118654752f));
      else if (act==3) v = fmaxf(v,0.f) + log1pf(__expf(-fabsf(v)));
      if (outBf) ((bf16*)Cb)[zb*sCb + zh*sCh + (long long)m*sCm + n] = f2bf(v);
      else       ((float*)Cb)[zb*sCb + zh*sCh + (long long)m*sCm + n] = v;
    }
  }
}

// ---------------- flash attention (bf16 in, bf16 out) ----------------
// block: (64-q tile, z=b*8+h). Q/K/V bf16 strided: [((pos*BB+b)*ld + off + hoff + d].
// O bf16 [(q*BB+b)*512+hoff+d]. If Pout: pass 2 writes normalized P (bf16) at Pout[z*1M+q*1024+k].
__global__ __launch_bounds__(256) void k_flash(
    const bf16* __restrict__ Qb, int ldq, int qoff,
    const bf16* __restrict__ Kb, int ldk, int koff,
    const bf16* __restrict__ Vb, int ldv, int voff,
    bf16* __restrict__ O, bf16* __restrict__ Pout, float scale)
{
  __shared__ short Qs[64*40];
  __shared__ short Ks[64*40];
  __shared__ short Vs[64*40];   // transposed: Vs[d][kpos]
  __shared__ short Ps[64*40];
  const int tid = threadIdx.x;
  int bx = blockIdx.x, by = blockIdx.y;
  {  // same-z blocks onto one XCD
    int gx = gridDim.x;
    int lin = by*gx + bx;
    int xcd = lin & 7, i = lin >> 3;
    by = xcd*(gridDim.y >> 3) + i / gx;
    bx = i % gx;
  }
  const int q0 = bx << 6;
  const int z = by; const int b = z >> 3; const int hoff = (z & 7) << 6;
  const int lane = tid & 63, w = tid >> 6;
  const int lr = lane & 15, quad = lane >> 4;

  // stage Q once
  #pragma unroll
  for (int i=0;i<2;++i){
    int idx = tid + i*256;
    int row = idx >> 3, d8 = (idx & 7) << 3;
    *(short8v*)&Qs[row*40 + d8] =
      *(const short8v*)&Qb[(size_t)((q0+row)*BB + b)*ldq + qoff + hoff + d8];
  }

  float m_r[4], l_r[4];
  #pragma unroll
  for (int r=0;r<4;++r){ m_r[r] = -1e30f; l_r[r] = 0.f; }
  float4v acc_o[4];
  #pragma unroll
  for (int cb=0;cb<4;++cb) acc_o[cb] = (float4v)(0.f);

  // prefetch K/V tile 0 into regs
  short8v kr[2], vr[2];
  #pragma unroll
  for (int i=0;i<2;++i){
    int idx = tid + i*256;
    int row = idx >> 3, d8 = (idx & 7) << 3;
    kr[i] = *(const short8v*)&Kb[(size_t)(row*BB + b)*ldk + koff + hoff + d8];
    vr[i] = *(const short8v*)&Vb[(size_t)(row*BB + b)*ldv + voff + hoff + d8];
  }

  for (int kt=0; kt<16; ++kt){
    __syncthreads();
    #pragma unroll
    for (int i=0;i<2;++i){
      int idx = tid + i*256;
      int row = idx >> 3, d8 = (idx & 7) << 3;   // row = kpos
      *(short8v*)&Ks[row*40 + d8] = kr[i];
      #pragma unroll
      for (int j=0;j<8;++j) Vs[(d8+j)*40 + row] = vr[i][j];
    }
    if (kt < 15){
      #pragma unroll
      for (int i=0;i<2;++i){
        int idx = tid + i*256;
        int row = ((kt+1)<<6) + (idx >> 3); int d8 = (idx & 7) << 3;
        kr[i] = *(const short8v*)&Kb[(size_t)(row*BB + b)*ldk + koff + hoff + d8];
        vr[i] = *(const short8v*)&Vb[(size_t)(row*BB + b)*ldv + voff + hoff + d8];
      }
    }
    __syncthreads();
    short8v a0 = *(short8v*)&Qs[(w*16+lr)*40 + quad*8];
    short8v a1 = *(short8v*)&Qs[(w*16+lr)*40 + quad*8 + 32];
    float4v s[4];
    #pragma unroll
    for (int cb=0;cb<4;++cb){
      short8v b0 = *(short8v*)&Ks[(cb*16+lr)*40 + quad*8];
      short8v b1 = *(short8v*)&Ks[(cb*16+lr)*40 + quad*8 + 32];
      float4v t = __builtin_amdgcn_mfma_f32_16x16x32_bf16(a0, b0, (float4v)(0.f), 0,0,0);
      s[cb] = __builtin_amdgcn_mfma_f32_16x16x32_bf16(a1, b1, t, 0,0,0);
    }
    #pragma unroll
    for (int cb=0;cb<4;++cb)
      #pragma unroll
      for (int r=0;r<4;++r) s[cb][r] *= scale;
    float al[4];
    #pragma unroll
    for (int r=0;r<4;++r){
      float mx = fmaxf(fmaxf(s[0][r],s[1][r]),fmaxf(s[2][r],s[3][r]));
      #pragma unroll
      for (int ofs=1; ofs<16; ofs<<=1) mx = fmaxf(mx, __shfl_xor(mx, ofs));
      float mnew = fmaxf(m_r[r], mx);
      al[r] = __expf(m_r[r] - mnew);
      float sum = 0.f;
      #pragma unroll
      for (int cb=0;cb<4;++cb){
        float p = __expf(s[cb][r] - mnew);
        s[cb][r] = p;
        sum += p;
      }
      #pragma unroll
      for (int ofs=1; ofs<16; ofs<<=1) sum += __shfl_xor(sum, ofs);
      l_r[r] = l_r[r]*al[r] + sum;
      m_r[r] = mnew;
    }
    #pragma unroll
    for (int cb=0;cb<4;++cb)
      #pragma unroll
      for (int r=0;r<4;++r){
        acc_o[cb][r] *= al[r];
        Ps[(w*16 + quad*4 + r)*40 + cb*16 + lr] = f2bfs(s[cb][r]);
      }
    __syncthreads();
    short8v p0 = *(short8v*)&Ps[(w*16+lr)*40 + quad*8];
    short8v p1 = *(short8v*)&Ps[(w*16+lr)*40 + quad*8 + 32];
    #pragma unroll
    for (int cb=0;cb<4;++cb){
      short8v v0 = *(short8v*)&Vs[(cb*16+lr)*40 + quad*8];
      short8v v1 = *(short8v*)&Vs[(cb*16+lr)*40 + quad*8 + 32];
      acc_o[cb] = __builtin_amdgcn_mfma_f32_16x16x32_bf16(p0, v0, acc_o[cb], 0,0,0);
      acc_o[cb] = __builtin_amdgcn_mfma_f32_16x16x32_bf16(p1, v1, acc_o[cb], 0,0,0);
    }
  }
  float linv[4];
  #pragma unroll
  for (int r=0;r<4;++r) linv[r] = 1.f/l_r[r];
  #pragma unroll
  for (int cb=0;cb<4;++cb)
    #pragma unroll
    for (int r=0;r<4;++r){
      int q = q0 + w*16 + quad*4 + r;
      O[(size_t)(q*BB + b)*512 + hoff + cb*16 + lr] = f2bf(acc_o[cb][r]*linv[r]);
    }

  if (Pout){
    bf16* Pz = Pout + (size_t)z*(1u<<20);
    for (int kt=0; kt<16; ++kt){
      __syncthreads();
      #pragma unroll
      for (int i=0;i<2;++i){
        int idx = tid + i*256;
        int row = idx >> 3, d8 = (idx & 7) << 3;
        *(short8v*)&Ks[row*40 + d8] =
          *(const short8v*)&Kb[(size_t)(((kt<<6)+row)*BB + b)*ldk + koff + hoff + d8];
      }
      __syncthreads();
      short8v a0 = *(short8v*)&Qs[(w*16+lr)*40 + quad*8];
      short8v a1 = *(short8v*)&Qs[(w*16+lr)*40 + quad*8 + 32];
      #pragma unroll
      for (int cb=0;cb<4;++cb){
        short8v b0 = *(short8v*)&Ks[(cb*16+lr)*40 + quad*8];
        short8v b1 = *(short8v*)&Ks[(cb*16+lr)*40 + quad*8 + 32];
        float4v t = __builtin_amdgcn_mfma_f32_16x16x32_bf16(a0, b0, (float4v)(0.f), 0,0,0);
        t = __builtin_amdgcn_mfma_f32_16x16x32_bf16(a1, b1, t, 0,0,0);
        #pragma unroll
        for (int r=0;r<4;++r){
          float p = __expf(t[r]*scale - m_r[r]) * linv[r];
          Pz[(size_t)(q0 + w*16 + quad*4 + r)*1024 + (kt<<6) + cb*16 + lr] = f2bf(p);
        }
      }
    }
  }
}

// ---------------- mean over heads (bf16 P) -> output ----------------
__global__ __launch_bounds__(256) void k_attn_mean_b(const bf16* __restrict__ P, void* __restrict__ out,
                                                     const int* __restrict__ flag){
  int idx = blockIdx.x*256 + threadIdx.x;  // 2M
  int b = idx >> 20; int rem = idx & ((1<<20)-1);
  const bf16* p = P + (size_t)b*HH*(1u<<20) + rem;
  float s = 0.f;
  #pragma unroll
  for (int h=0;h<HH;++h) s += bf2f(p[(size_t)h*(1u<<20)]);
  s *= 0.125f;
  size_t o = (size_t)(1u<<20) + (size_t)idx;
  if (flag[0]) ((bf16*)out)[o] = f2bf(s);
  else         ((float*)out)[o] = s;
}

// ---------------- norms / elementwise ----------------
__global__ __launch_bounds__(256) void k_add_rmsnorm(float* __restrict__ x, const float* __restrict__ t2, const float* __restrict__ w){
  int row = blockIdx.x; size_t base = (size_t)row*DD;
  int tid = threadIdx.x;
  float v0 = x[base+tid] + t2[base+tid];
  float v1 = x[base+tid+256] + t2[base+tid+256];
  __shared__ float red[256];
  red[tid] = v0*v0 + v1*v1; __syncthreads();
  for (int s=128;s>0;s>>=1){ if(tid<s) red[tid]+=red[tid+s]; __syncthreads(); }
  float rms = rsqrtf(red[0]*(1.f/DD) + EPSF);
  x[base+tid]     = v0 * w[tid]     * rms;
  x[base+tid+256] = v1 * w[tid+256] * rms;
}

__global__ __launch_bounds__(256) void k_add_rmsnorm_out(const float* __restrict__ x, const float* __restrict__ t2,
                                                         const float* __restrict__ w, void* __restrict__ out,
                                                         const int* __restrict__ flag){
  int row = blockIdx.x; size_t base = (size_t)row*DD;
  int tid = threadIdx.x;
  float v0 = x[base+tid] + t2[base+tid];
  float v1 = x[base+tid+256] + t2[base+tid+256];
  __shared__ float red[256];
  red[tid] = v0*v0 + v1*v1; __syncthreads();
  for (int s=128;s>0;s>>=1){ if(tid<s) red[tid]+=red[tid+s]; __syncthreads(); }
  float rms = rsqrtf(red[0]*(1.f/DD) + EPSF);
  float o0 = v0 * w[tid]     * rms;
  float o1 = v1 * w[tid+256] * rms;
  if (flag[0]){ ((bf16*)out)[base+tid] = f2bf(o0); ((bf16*)out)[base+tid+256] = f2bf(o1); }
  else        { ((float*)out)[base+tid] = o0;      ((float*)out)[base+tid+256] = o1; }
}

__global__ __launch_bounds__(256) void k_trans_layernorm(const float* __restrict__ tgt, const float* __restrict__ w, const float* __restrict__ bias, bf16* __restrict__ xn){
  int r = blockIdx.x;        // b*L + l
  int b = r >> 10, l = r & 1023;
  size_t src = ((size_t)l*BB + b)*DD;
  int tid = threadIdx.x;
  float v0 = tgt[src+tid], v1 = tgt[src+tid+256];
  __shared__ float red[256];
  red[tid] = v0 + v1; __syncthreads();
  for (int s=128;s>0;s>>=1){ if(tid<s) red[tid]+=red[tid+s]; __syncthreads(); }
  float mean = red[0]*(1.f/DD);
  __syncthreads();
  red[tid] = v0*v0 + v1*v1; __syncthreads();
  for (int s=128;s>0;s>>=1){ if(tid<s) red[tid]+=red[tid+s]; __syncthreads(); }
  float var = red[0]*(1.f/DD) - mean*mean;
  float rstd = rsqrtf(var + EPSF);
  size_t dst = (size_t)r*DD;
  xn[dst+tid]     = f2bf((v0-mean)*rstd*w[tid]     + bias[tid]);
  xn[dst+tid+256] = f2bf((v1-mean)*rstd*w[tid+256] + bias[tid+256]);
}

__global__ __launch_bounds__(256) void k_combine_ln(const float* __restrict__ yf, const float* __restrict__ yb, const float* __restrict__ w, const float* __restrict__ bias, bf16* __restrict__ mo){
  int r = blockIdx.x; int b = r>>10, l = r&1023;
  size_t rf = (size_t)r*DD;
  size_t rb = ((size_t)(b<<10) + (1023 - l))*DD;
  int tid = threadIdx.x;
  float v0 = yf[rf+tid]     + yb[rb+tid];
  float v1 = yf[rf+tid+256] + yb[rb+tid+256];
  __shared__ float red[256];
  red[tid] = v0 + v1; __syncthreads();
  for (int s=128;s>0;s>>=1){ if(tid<s) red[tid]+=red[tid+s]; __syncthreads(); }
  float mean = red[0]*(1.f/DD);
  __syncthreads();
  red[tid] = v0*v0 + v1*v1; __syncthreads();
  for (int s=128;s>0;s>>=1){ if(tid<s) red[tid]+=red[tid+s]; __syncthreads(); }
  float var = red[0]*(1.f/DD) - mean*mean;
  float rstd = rsqrtf(var + EPSF);
  mo[rf+tid]     = f2bf((v0-mean)*rstd*w[tid]     + bias[tid]);
  mo[rf+tid+256] = f2bf((v1-mean)*rstd*w[tid+256] + bias[tid+256]);
}

__global__ __launch_bounds__(256) void k_bimamba_final(float* __restrict__ tgt, const float* __restrict__ ffo, const float* __restrict__ w){
  int r = blockIdx.x; int b = r>>10, l = r&1023;
  size_t t = ((size_t)l*BB + b)*DD;
  size_t f = (size_t)r*DD;
  int tid = threadIdx.x;
  float v0 = 2.f*tgt[t+tid]     + ffo[f+tid];
  float v1 = 2.f*tgt[t+tid+256] + ffo[f+tid+256];
  __shared__ float red[256];
  red[tid] = v0*v0 + v1*v1; __syncthreads();
  for (int s=128;s>0;s>>=1){ if(tid<s) red[tid]+=red[tid+s]; __syncthreads(); }
  float rms = rsqrtf(red[0]*(1.f/DD) + EPSF);
  tgt[t+tid]     = v0 * w[tid]     * rms;
  tgt[t+tid+256] = v1 * w[tid+256] * rms;
}

// ---------------- causal depthwise conv + silu ----------------
__global__ __launch_bounds__(256) void k_conv_silu(const float* __restrict__ xz, const float* __restrict__ cw, const float* __restrict__ cb, float* __restrict__ xmc){
  int rev = blockIdx.y;
  int idx = blockIdx.x*256 + threadIdx.x;  // 2M
  int c = idx & 1023;
  int l = (idx >> 10) & 1023;
  int b = idx >> 20;
  float acc = cb[c];
  float w4[4];
  #pragma unroll
  for (int j=0;j<4;++j) w4[j] = cw[(c<<2)+j];
  #pragma unroll
  for (int j=0;j<4;++j){
    int t = l - 3 + j;
    if (t >= 0){
      int src = rev ? (1023 - t) : t;
      acc = fmaf(w4[j], xz[((size_t)(b<<10) + src)*2048 + c], acc);
    }
  }
  xmc[(size_t)rev*(2u<<20) + idx] = acc / (1.f + __expf(-acc));
}

// ---------------- chunked selective scan ----------------
__global__ __launch_bounds__(256) void k_scan1(
    const float* __restrict__ delta_f, const float* __restrict__ delta_b,
    const float* __restrict__ xmc_f,  const float* __restrict__ xmc_b,
    const float* __restrict__ dbc_f,  const float* __restrict__ dbc_b,
    const float* __restrict__ Alog,
    float* __restrict__ hend, float* __restrict__ Sdl)
{
  int ch = blockIdx.x*256 + threadIdx.x;
  int c = blockIdx.y;
  int dir = ch >> 11, b = (ch >> 10) & 1, d = ch & 1023;
  const float* delta = dir ? delta_b : delta_f;
  const float* xmc   = dir ? xmc_b   : xmc_f;
  const float* dbc   = dir ? dbc_b   : dbc_f;
  float Av[NSTATE];
  #pragma unroll
  for (int n=0;n<NSTATE;++n) Av[n] = -__expf(Alog[d*NSTATE+n]);
  float h[NSTATE];
  #pragma unroll
  for (int n=0;n<NSTATE;++n) h[n]=0.f;
  float S = 0.f;
  int r0 = b*1024 + c*32;
  for (int t=0;t<32;++t){
    int r = r0 + t;
    float dl = delta[((size_t)r<<10) + d];
    float x  = xmc[((size_t)r<<10) + d];
    const float4* bp = (const float4*)(dbc + (size_t)r*64 + 32);
    float Bv[NSTATE];
    ((float4*)Bv)[0]=bp[0]; ((float4*)Bv)[1]=bp[1]; ((float4*)Bv)[2]=bp[2]; ((float4*)Bv)[3]=bp[3];
    S += dl;
    float dx = dl*x;
    #pragma unroll
    for (int n=0;n<NSTATE;++n){
      float dA = __expf(dl*Av[n]);
      h[n] = fmaf(dA, h[n], dx*Bv[n]);
    }
  }
  size_t base = ((size_t)c*4096 + ch)*16;
  #pragma unroll
  for (int n=0;n<NSTATE;++n) hend[base+n] = h[n];
  Sdl[c*4096 + ch] = S;
}

// parallel over (channel, state): 65536 independent chains
__global__ __launch_bounds__(256) void k_scan_carry(const float* __restrict__ Alog,
                                                    float* __restrict__ hh, const float* __restrict__ Sdl)
{
  int g = blockIdx.x*256 + threadIdx.x;   // 65536
  int ch = g >> 4, n = g & 15;
  int d = ch & 1023;
  float Av = -__expf(Alog[d*16+n]);
  float h = 0.f;
  for (int c=0;c<32;++c){
    size_t base = ((size_t)c*4096 + ch)*16 + n;
    float he = hh[base];
    hh[base] = h;
    h = fmaf(__expf(Av*Sdl[c*4096+ch]), h, he);
  }
}

__global__ __launch_bounds__(256) void k_scan2(
    const float* __restrict__ delta_f, const float* __restrict__ delta_b,
    const float* __restrict__ xmc_f,  const float* __restrict__ xmc_b,
    const float* __restrict__ dbc_f,  const float* __restrict__ dbc_b,
    const float* __restrict__ Alog,   const float* __restrict__ hin,
    float* __restrict__ y_f, float* __restrict__ y_b)
{
  int ch = blockIdx.x*256 + threadIdx.x;
  int c = blockIdx.y;
  int dir = ch >> 11, b = (ch >> 10) & 1, d = ch & 1023;
  const float* delta = dir ? delta_b : delta_f;
  const float* xmc   = dir ? xmc_b   : xmc_f;
  const float* dbc   = dir ? dbc_b   : dbc_f;
  float* y           = dir ? y_b     : y_f;
  float Av[NSTATE];
  #pragma unroll
  for (int n=0;n<NSTATE;++n) Av[n] = -__expf(Alog[d*NSTATE+n]);
  float h[NSTATE];
  size_t cbase = ((size_t)c*4096 + ch)*16;
  #pragma unroll
  for (int n=0;n<NSTATE;++n) h[n] = hin[cbase+n];
  int r0 = b*1024 + c*32;
  for (int t=0;t<32;++t){
    int r = r0 + t;
    float dl = delta[((size_t)r<<10) + d];
    float x  = xmc[((size_t)r<<10) + d];
    const float4* bp = (const float4*)(dbc + (size_t)r*64 + 32);
    float Bv[NSTATE], Cv[NSTATE];
    ((float4*)Bv)[0]=bp[0]; ((float4*)Bv)[1]=bp[1]; ((float4*)Bv)[2]=bp[2]; ((float4*)Bv)[3]=bp[3];
    ((float4*)Cv)[0]=bp[4]; ((float4*)Cv)[1]=bp[5]; ((float4*)Cv)[2]=bp[6]; ((float4*)Cv)[3]=bp[7];
    float dx = dl*x;
    float acc = 0.f;
    #pragma unroll
    for (int n=0;n<NSTATE;++n){
      float dA = __expf(dl*Av[n]);
      h[n] = fmaf(dA, h[n], dx*Bv[n]);
      acc = fmaf(h[n], Cv[n], acc);
    }
    y[((size_t)r<<10) + d] = acc;
  }
}

// ---------------- y_out(bf16) = (y + Dp*xmc) * silu(z) ----------------
__global__ __launch_bounds__(256) void k_gate(const float* __restrict__ y, const float* __restrict__ xmc, const float* __restrict__ xz, const float* __restrict__ Dp, bf16* __restrict__ yo){
  int rev = blockIdx.y;
  int idx = blockIdx.x*256 + threadIdx.x;  // 2M
  int c = idx & 1023;
  int l = (idx >> 10) & 1023;
  int b = idx >> 20;
  int src = rev ? (1023 - l) : l;
  float z = xz[((size_t)(b<<10)+src)*2048 + 1024 + c];
  float s = z / (1.f + __expf(-z));
  size_t o = (size_t)rev*(2u<<20) + idx;
  yo[o] = f2bf((y[o] + Dp[c]*xmc[o]) * s);
}

extern "C" void kernel_launch(void* const* d_in, const int* in_sizes, int n_in,
                              void* d_out, int out_size, void* d_ws, size_t ws_size,
                              hipStream_t stream)
{
  if (n_in < 37) return;
  static const unsigned int SZ[37] = {
    1048576,1048576,786432,1536,262144,512,786432,1536,262144,512,
    512,512,512,512,1048576,2048,1048576,512,512,512,
    512,512,1048576,2048,1048576,512,1048576,2048,4096,1024,
    65536,32768,1024,16384,1024,524288,512
  };
  static const unsigned char ISW[37] = {
    0,0,1,0,1,0,1,0,1,0, 0,0,0,0,1,0,1,0,0,0,
    0,0,1,0,1,0,1,0,0,0, 1,1,0,0,0,1,0
  };
  const long long MF = 1u<<20;
  if (ws_size < (size_t)(32*MF)*sizeof(float)) return;   // 128 MB

  float* ws = (float*)d_ws;
  float* inF = ws;                       // fp32 params arena  [0, 3MF)
  bf16*  inB = (bf16*)(ws + 3*MF);       // bf16 weight arena  [3MF, 7MF)
  float* t2    = ws + 7*MF;
  float* mbuf  = ws + 8*MF;
  float* proj  = ws + 9*MF;              // 3MF
  float* big   = ws + 12*MF;             // 16MF
  float* ff1   = ws + 28*MF;             // 2MF as bf16 (4M els)
  float* hend  = ws + 30*MF;             // 2MF

  CvtTabF tf; CvtTabW tb;
  unsigned int fOff[37], bOff[37];
  {
    int nf=0, nb=0; unsigned int of=0, ob=0;
    for (int i=0;i<37;++i){
      if (ISW[i]){ tb.src[nb]=d_in[i]; tb.off[nb]=ob; bOff[i]=ob; ob+=SZ[i]; ++nb; }
      else       { tf.src[nf]=d_in[i]; tf.off[nf]=of; fOff[i]=of; of+=SZ[i]; ++nf; }
    }
    tf.off[25]=of; tb.off[12]=ob;
    int* flag = (int*)(ws + 3*MF - 16);

    #define PF(i) (inF + fOff[i])
    #define PW(i) (inB + bOff[i])

    float* tgt_f = PF(0);
    float* mem_f = PF(1);
    bf16* qkvB   = (bf16*)proj;          // 3M els
    bf16* qB     = (bf16*)proj;          // 1M els (CA)
    bf16* kvB    = (bf16*)(proj + 1*MF); // 2M els (CA)
    bf16* attnoB = (bf16*)mbuf;          // 1M els
    bf16* xnB    = (bf16*)t2;            // 1M els
    float* xz      = big;
    float* xmc_f   = big + 4*MF;
    float* xmc_b   = xmc_f + 2*MF;
    float* delta_f = big + 8*MF;
    float* delta_b = big + 10*MF;
    float* y_f     = big + 12*MF;
    float* y_b     = y_f + 2*MF;
    bf16*  ybf     = (bf16*)(big + 8*MF);   // 4M els, overlays dead delta
    float* dbc_f   = proj;
    float* dbc_b   = proj + 131072;
    float* Sdl     = proj + 262144;         // 128K floats
    float* yproj_f = proj + 1*MF;
    float* yproj_b = proj + 2*MF;
    float* ffo     = mem_f;
    bf16*  ff1B    = (bf16*)ff1;            // 4M els
    bf16*  mbufB   = (bf16*)mbuf;

    k_detect<<<1,256,0,stream>>>((const unsigned int*)d_in[0], flag);
    k_cvt_f32<<<2048,256,0,stream>>>(tf, inF, flag, (int)of);
    k_cvt_b16<<<4096,256,0,stream>>>(tb, inB, flag, (int)ob);

    // ---- self attention ----
    k_mfma_gemm<<<dim3(24,32,1),256,0,stream>>>(tgt_f,0,0,0,512, PW(2),0,0,512,2, qkvB,1,0,0,1536, PF(3),1.f,0,512,1);
    k_flash<<<dim3(16,16),256,0,stream>>>(qkvB,1536,0, qkvB,1536,512, qkvB,1536,1024, attnoB, nullptr, 0.125f);
    k_mfma_gemm<<<dim3(8,32,1),256,0,stream>>>(attnoB,1,0,0,512, PW(4),0,0,512,2, t2,0,0,0,512, PF(5),1.f,0,512,1);
    k_add_rmsnorm<<<2048,256,0,stream>>>(tgt_f, t2, PF(10));

    // ---- cross attention ----
    k_mfma_gemm<<<dim3(8,32,1),256,0,stream>>>(tgt_f,0,0,0,512, PW(6),0,0,512,2, qB,1,0,0,512, PF(7),1.f,0,512,1);
    k_mfma_gemm<<<dim3(16,32,1),256,0,stream>>>(mem_f,0,0,0,512, PW(6)+(size_t)512*512,0,0,512,2, kvB,1,0,0,1024, PF(7)+512,1.f,0,512,1);
    k_flash<<<dim3(16,16),256,0,stream>>>(qB,512,0, kvB,1024,0, kvB,1024,512, attnoB, (bf16*)big, 0.125f);
    k_attn_mean_b<<<8192,256,0,stream>>>((const bf16*)big, d_out, flag);
    k_mfma_gemm<<<dim3(8,32,1),256,0,stream>>>(attnoB,1,0,0,512, PW(8),0,0,512,2, t2,0,0,0,512, PF(9),1.f,0,512,1);
    k_add_rmsnorm<<<2048,256,0,stream>>>(tgt_f, t2, PF(11));

    // ---- bimamba ----
    k_trans_layernorm<<<2048,256,0,stream>>>(tgt_f, PF(18), PF(19), xnB);
    k_mfma_gemm<<<dim3(32,32,1),256,0,stream>>>(xnB,1,0,0,512, PW(26),0,0,512,2, xz,0,0,0,2048, PF(27),1.f,0,512,1);
    k_conv_silu<<<dim3(8192,2),256,0,stream>>>(xz, PF(28), PF(29), xmc_f);
    k_mfma_gemm<<<dim3(1,32,2),256,0,stream>>>(xmc_f,0,2*MF,0,1024, PW(30),0,0,1024,2, dbc_f,0,131072,0,64, nullptr,1.f,0,1024,1);
    k_mfma_gemm<<<dim3(16,32,2),256,0,stream>>>(dbc_f,0,131072,0,64, PW(31),0,0,32,2, delta_f,0,2*MF,0,1024, PF(32),1.f,3,32,1);
    k_scan1<<<dim3(16,32),256,0,stream>>>(delta_f,delta_b,xmc_f,xmc_b,dbc_f,dbc_b, PF(33), hend, Sdl);
    k_scan_carry<<<256,256,0,stream>>>(PF(33), hend, Sdl);
    k_scan2<<<dim3(16,32),256,0,stream>>>(delta_f,delta_b,xmc_f,xmc_b,dbc_f,dbc_b, PF(33), hend, y_f, y_b);
    k_gate<<<dim3(8192,2),256,0,stream>>>(y_f, xmc_f, xz, PF(34), ybf);
    k_mfma_gemm<<<dim3(8,32,2),256,0,stream>>>(ybf,1,2*MF,0,1024, PW(35),0,0,1024,2, yproj_f,0,1*MF,0,512, PF(36),1.f,0,1024,1);
    k_combine_ln<<<2048,256,0,stream>>>(yproj_f, yproj_b, PF(20), PF(21), mbufB);
    k_mfma_gemm<<<dim3(32,32,1),256,0,stream>>>(mbufB,1,0,0,512, PW(22),0,0,512,2, ff1B,1,0,0,2048, PF(23),1.f,2,512,1);
    k_mfma_gemm<<<dim3(8,32,1),256,0,stream>>>(ff1B,1,0,0,2048, PW(24),0,0,2048,2, ffo,0,0,0,512, PF(25),1.f,0,2048,1);
    k_bimamba_final<<<2048,256,0,stream>>>(tgt_f, ffo, PF(12));

    // ---- final FFN ----
    k_mfma_gemm<<<dim3(32,32,1),256,0,stream>>>(tgt_f,0,0,0,512, PW(14),0,0,512,2, ff1B,1,0,0,2048, PF(15),1.f,1,512,1);
    k_mfma_gemm<<<dim3(8,32,1),256,0,stream>>>(ff1B,1,0,0,2048, PW(16),0,0,2048,2, t2,0,0,0,512, PF(17),1.f,0,2048,1);
    k_add_rmsnorm_out<<<2048,256,0,stream>>>(tgt_f, t2, PF(13), d_out, flag);
    #undef PF
    #undef PW
  }
}